// Round 13
// baseline (216.929 us; speedup 1.0000x reference)
//
#include <hip/hip_runtime.h>

// NonLocalAttentionStack on MI355X.
// Dims: B=1, T=4, C=128, H=W=96, NHEADS=4 (c=32/head), WS=7 (49 cands), PS=3, K=16.
// Pipeline: prep -> ln_stats -> QKV (fp32 GEMM; v output bf16) ->
//           search+topk+softmax (fp32, 16x16 tile, rolling k-band, batched-7dx) ->
//           fused gather+implicit-conv MFMA GEMM (XCD-swizzled, LDS dbuf,
//           row-pair chunk-XOR swizzle (0 conflicts), T14 prefetch for v AND B).

typedef float  f32x4  __attribute__((ext_vector_type(4)));
typedef __bf16 bf16x8 __attribute__((ext_vector_type(8)));
typedef __bf16 bf16x4 __attribute__((ext_vector_type(4)));

__device__ __forceinline__ float dpp_shr1(float x) {  // lane L gets lane L-1 (16-lane rows)
  return __int_as_float(__builtin_amdgcn_update_dpp(0, __float_as_int(x), 0x111, 0xf, 0xf, false));
}
__device__ __forceinline__ float dpp_shl1(float x) {  // lane L gets lane L+1
  return __int_as_float(__builtin_amdgcn_update_dpp(0, __float_as_int(x), 0x101, 0xf, 0xf, false));
}

// ---------------------------------------------------------------------------
// prep: Wt[c][o=384] = {wq|wk|wv}[o][c];  pwt[g][kd][d=9][o=32][i=32] bf16
// ---------------------------------------------------------------------------
__global__ __launch_bounds__(256) void prep_kernel(
    const float* __restrict__ wq, const float* __restrict__ wk, const float* __restrict__ wv,
    const float* __restrict__ pw, float* __restrict__ Wt, __bf16* __restrict__ pwt) {
  int idx = blockIdx.x * 256 + threadIdx.x;
  const int NPW = 4 * 16 * 9 * 32 * 32;  // 589824
  if (idx < NPW) {
    int i  = idx & 31;
    int ol = (idx >> 5) & 31;
    int d  = (idx >> 10) % 9;
    int r  = (idx >> 10) / 9;   // g*16+kd
    int kd = r & 15;
    int g  = r >> 4;
    int o  = g * 32 + ol;
    pwt[idx] = (__bf16)pw[((o * 32 + i) * 16 + kd) * 9 + d];
  } else {
    int widx = idx - NPW;
    if (widx < 128 * 384) {
      int o = widx % 384;
      int c = widx / 384;
      const float* __restrict__ src = (o < 128) ? wq : (o < 256 ? wk : wv);
      Wt[widx] = src[(o & 127) * 128 + c];
    }
  }
}

// ---------------------------------------------------------------------------
// LN stats: per-pixel mean / rsqrt(var+eps).  grid (144,4) x 64 threads.
// ---------------------------------------------------------------------------
__global__ __launch_bounds__(64) void ln_stats_kernel(
    const float* __restrict__ vid, float* __restrict__ mu, float* __restrict__ rs) {
  int pix = blockIdx.x * 64 + threadIdx.x;
  int f = blockIdx.y;
  const float* __restrict__ vp = vid + (size_t)f * 128 * 9216 + pix;
  float s = 0.f, s2 = 0.f;
  #pragma unroll 8
  for (int c = 0; c < 128; ++c) { float x = vp[(size_t)c * 9216]; s += x; s2 += x * x; }
  float m_ = s * (1.f / 128.f);
  float v_ = fmaxf(s2 * (1.f / 128.f) - m_ * m_, 0.f);
  mu[f * 9216 + pix] = m_;
  rs[f * 9216 + pix] = rsqrtf(v_ + 1e-6f);
}

// ---------------------------------------------------------------------------
// QKV GEMM: 128x128 tile, K=128 in 4x32 chunks, 512 threads (8 waves),
// register double-buffered staging.  grid (3, 288); blockIdx.x selects q/k/v.
// q,k: fp32 [t*4+head][pix][c32].  v: bf16 same layout.
// ---------------------------------------------------------------------------
__global__ __launch_bounds__(512) void qkv_gemm_kernel(
    const float* __restrict__ vid, const float* __restrict__ mu, const float* __restrict__ rs,
    const float* __restrict__ lnw, const float* __restrict__ lnb,
    const float* __restrict__ Wt, const float* __restrict__ bq, const float* __restrict__ bk,
    const float* __restrict__ bv, float* __restrict__ qb, float* __restrict__ kb,
    __bf16* __restrict__ vbbf) {
  __shared__ __align__(16) float Xs[32][128];
  __shared__ __align__(16) float Ws[32][128];
  __shared__ float muL[128], rsL[128], lwS[128], lbS[128];
  int tid = threadIdx.x;
  int mt = blockIdx.y;
  int N0 = blockIdx.x * 128;
  int f  = mt / 72;
  int pf = (mt % 72) * 128;

  if (tid < 128) {
    muL[tid] = mu[f * 9216 + pf + tid];
    rsL[tid] = rs[f * 9216 + pf + tid];
  } else if (tid < 256) {
    int t2 = tid - 128;
    lwS[t2] = lnw[t2];
    lbS[t2] = lnb[t2];
  }

  int tx = tid & 15, ty = tid >> 4;   // ty 0..31
  int m0 = ty * 4;
  int sm = tid & 127;                  // staging column
  int sk = tid >> 7;                   // staging row base (0..3)
  float acc[4][8];
  #pragma unroll
  for (int a = 0; a < 4; ++a)
    #pragma unroll
    for (int b = 0; b < 8; ++b) acc[a][b] = 0.f;

  const size_t vbase = (size_t)f * 128 * 9216 + pf;
  float xr[8], wr[8];

  #pragma unroll
  for (int it = 0; it < 8; ++it) {
    int kk = sk + 4 * it;
    xr[it] = vid[vbase + (size_t)kk * 9216 + sm];
    wr[it] = Wt[(size_t)kk * 384 + N0 + sm];
  }
  __syncthreads();
  #pragma unroll
  for (int it = 0; it < 8; ++it) {
    int kk = sk + 4 * it;
    Xs[kk][sm] = (xr[it] - muL[sm]) * rsL[sm] * lwS[kk] + lbS[kk];
    Ws[kk][sm] = wr[it];
  }
  __syncthreads();

  for (int kc = 0; kc < 4; ++kc) {
    if (kc < 3) {
      #pragma unroll
      for (int it = 0; it < 8; ++it) {
        int kk = sk + 4 * it;
        int c = (kc + 1) * 32 + kk;
        xr[it] = vid[vbase + (size_t)c * 9216 + sm];
        wr[it] = Wt[(size_t)c * 384 + N0 + sm];
      }
    }
    #pragma unroll 4
    for (int kk = 0; kk < 32; ++kk) {
      float xa[4], wa[8];
      *(float4*)&xa[0] = *(const float4*)&Xs[kk][m0];
      *(float4*)&wa[0] = *(const float4*)&Ws[kk][tx * 4];
      *(float4*)&wa[4] = *(const float4*)&Ws[kk][64 + tx * 4];
      #pragma unroll
      for (int a = 0; a < 4; ++a)
        #pragma unroll
        for (int b = 0; b < 8; ++b)
          acc[a][b] = fmaf(xa[a], wa[b], acc[a][b]);
    }
    if (kc < 3) {
      __syncthreads();
      #pragma unroll
      for (int it = 0; it < 8; ++it) {
        int kk = sk + 4 * it;
        int c = (kc + 1) * 32 + kk;
        Xs[kk][sm] = (xr[it] - muL[sm]) * rsL[sm] * lwS[c] + lbS[c];
        Ws[kk][sm] = wr[it];
      }
      __syncthreads();
    }
  }

  int sel = blockIdx.x;
  int nlo = tx * 4, nhi = 64 + tx * 4;
  int hlo = nlo >> 5, clo = nlo & 31;
  int hhi = nhi >> 5, chi = nhi & 31;
  const float* __restrict__ bias = (sel == 0) ? bq : (sel == 1 ? bk : bv);
  float4 blo = make_float4(bias[nlo], bias[nlo + 1], bias[nlo + 2], bias[nlo + 3]);
  float4 bhi = make_float4(bias[nhi], bias[nhi + 1], bias[nhi + 2], bias[nhi + 3]);
  size_t base_lo = (size_t)(f * 4 + hlo) * 9216 * 32 + clo;
  size_t base_hi = (size_t)(f * 4 + hhi) * 9216 * 32 + chi;
  if (sel < 2) {
    float* __restrict__ dst = (sel == 0) ? qb : kb;
    #pragma unroll
    for (int a = 0; a < 4; ++a) {
      size_t poff = (size_t)(pf + m0 + a) * 32;
      *(float4*)&dst[base_lo + poff] = make_float4(acc[a][0] + blo.x, acc[a][1] + blo.y,
                                                   acc[a][2] + blo.z, acc[a][3] + blo.w);
      *(float4*)&dst[base_hi + poff] = make_float4(acc[a][4] + bhi.x, acc[a][5] + bhi.y,
                                                   acc[a][6] + bhi.z, acc[a][7] + bhi.w);
    }
  } else {
    #pragma unroll
    for (int a = 0; a < 4; ++a) {
      size_t poff = (size_t)(pf + m0 + a) * 32;
      bf16x4 lo4, hi4;
      lo4[0] = (__bf16)(acc[a][0] + blo.x); lo4[1] = (__bf16)(acc[a][1] + blo.y);
      lo4[2] = (__bf16)(acc[a][2] + blo.z); lo4[3] = (__bf16)(acc[a][3] + blo.w);
      hi4[0] = (__bf16)(acc[a][4] + bhi.x); hi4[1] = (__bf16)(acc[a][5] + bhi.y);
      hi4[2] = (__bf16)(acc[a][6] + bhi.z); hi4[3] = (__bf16)(acc[a][7] + bhi.w);
      *(bf16x4*)&vbbf[base_lo + poff] = lo4;
      *(bf16x4*)&vbbf[base_hi + poff] = hi4;
    }
  }
}

// ---------------------------------------------------------------------------
// search + topk + softmax.  16x16 s-region tile (inner 14x14 queries).
// Batched 7-dx rounds: 2 barriers per dy.  grid (49, 16), 256 threads.
// ---------------------------------------------------------------------------
__global__ __launch_bounds__(256, 3) void search_kernel(
    const float* __restrict__ qb, const float* __restrict__ kb,
    float* __restrict__ wgtb, int* __restrict__ indb) {
  __shared__ __align__(16) float klds[16 * 22 * 32];   // 45056 B
  __shared__ float slds[7][256];                        // 7168 B
  int tid = threadIdx.x;
  int th = blockIdx.y;
  int tile = blockIdx.x;
  int iy0 = (tile / 7) * 14, ix0 = (tile % 7) * 14;
  const float* __restrict__ kbase = kb + (size_t)th * 9216 * 32;

  #pragma unroll
  for (int it = 0; it < 11; ++it) {
    int i = it * 256 + tid;
    int r = i / 176, rem = i % 176;
    int col = rem >> 3, c4 = rem & 7;
    int gy = iy0 - 4 + r, gx = ix0 - 4 + col;
    float4 val = make_float4(0.f, 0.f, 0.f, 0.f);
    if ((unsigned)gy < 96u && (unsigned)gx < 96u)
      val = *(const float4*)&kbase[(size_t)(gy * 96 + gx) * 32 + c4 * 4];
    int p = r * 22 + col;
    *(float4*)&klds[p * 32 + ((c4 ^ (p & 7)) << 2)] = val;
  }

  int sy = tid >> 4, sx = tid & 15;
  int qy = iy0 - 1 + sy, qx = ix0 - 1 + sx;
  bool qok = (unsigned)qy < 96u && (unsigned)qx < 96u;
  float4 qv[8];
  #pragma unroll
  for (int j = 0; j < 8; ++j) qv[j] = make_float4(0.f, 0.f, 0.f, 0.f);
  if (qok) {
    const float* __restrict__ qp = qb + ((size_t)th * 9216 + qy * 96 + qx) * 32;
    #pragma unroll
    for (int j = 0; j < 8; ++j) qv[j] = *(const float4*)&qp[j * 4];
  }
  bool inner = (sy >= 1) && (sy <= 14) && (sx >= 1) && (sx <= 14) && qok;

  float tv[16]; int tix[16];
  #pragma unroll
  for (int j = 0; j < 16; ++j) { tv[j] = -3.0e38f; tix[j] = 0; }
  __syncthreads();

  #pragma unroll 1
  for (int dy = 0; dy < 7; ++dy) {
    if (dy > 0) {
      if (tid < 176) {
        int col = tid >> 3, c4 = tid & 7;
        int r = dy + 15;
        int gy = iy0 - 4 + r, gx = ix0 - 4 + col;
        float4 val = make_float4(0.f, 0.f, 0.f, 0.f);
        if ((unsigned)gy < 96u && (unsigned)gx < 96u)
          val = *(const float4*)&kbase[(size_t)(gy * 96 + gx) * 32 + c4 * 4];
        int p = (r & 15) * 22 + col;
        *(float4*)&klds[p * 32 + ((c4 ^ (p & 7)) << 2)] = val;
      }
      __syncthreads();
    }
    float h[7];
    #pragma unroll
    for (int dx = 0; dx < 7; ++dx) {
      int p = ((sy + dy) & 15) * 22 + (sx + dx);
      const float* __restrict__ kp = &klds[p * 32];
      int sw = p & 7;
      float sdot = 0.f;
      #pragma unroll
      for (int j = 0; j < 8; ++j) {
        float4 kq = *(const float4*)&kp[(j ^ sw) << 2];
        sdot += qv[j].x * kq.x + qv[j].y * kq.y + qv[j].z * kq.z + qv[j].w * kq.w;
      }
      h[dx] = sdot + dpp_shr1(sdot) + dpp_shl1(sdot);
      slds[dx][tid] = h[dx];
    }
    __syncthreads();
    if (inner) {
      #pragma unroll
      for (int dx = 0; dx < 7; ++dx) {
        float sc = h[dx] + slds[dx][tid - 16] + slds[dx][tid + 16];
        int oi = dy * 7 + dx;
        float cv = sc; int ci = oi;
        #pragma unroll
        for (int j = 0; j < 16; ++j) {
          bool gt = cv > tv[j];
          float mx = fmaxf(tv[j], cv);
          float mn = fminf(tv[j], cv);
          int nt = gt ? ci : tix[j];
          ci = gt ? tix[j] : ci;
          tv[j] = mx; cv = mn; tix[j] = nt;
        }
      }
    }
  }

  if (inner) {
    float mx = tv[0];
    float e[16], ssum = 0.f;
    #pragma unroll
    for (int j = 0; j < 16; ++j) { e[j] = __expf(tv[j] - mx); ssum += e[j]; }
    float inv = 1.f / ssum;
    size_t base = ((size_t)th * 9216 + qy * 96 + qx) * 16;
    #pragma unroll
    for (int j = 0; j < 4; ++j) {
      *(float4*)&wgtb[base + j * 4] =
          make_float4(e[j*4] * inv, e[j*4+1] * inv, e[j*4+2] * inv, e[j*4+3] * inv);
      *(int4*)&indb[base + j * 4] = make_int4(tix[j*4], tix[j*4+1], tix[j*4+2], tix[j*4+3]);
    }
  }
}

// ---------------------------------------------------------------------------
// fused gather + implicit-conv GEMM, XCD-swizzled.
// grid 576 (1D), 512 threads (8 waves x 2 rows).  16x16 px tile, 18x18 halo.
// A+B double-buffered in LDS -> ONE barrier per kd.  Row-pair chunk-XOR
// swizzle (conflicts measured 0).  T14 prefetch for v (2-deep), iw, AND B:
// pwt loads issued one phase early into br0..br2; phase only ds_writes them
// -> removes the per-phase L2 round-trip from the wave critical path.
// ---------------------------------------------------------------------------
#define STAGE_A(BUF, VR, WC) do {                                              \
  if (gact) {                                                                  \
    __bf16 tmp_[32];                                                           \
    _Pragma("unroll")                                                          \
    for (int wv_ = 0; wv_ < 4; ++wv_) {                                        \
      unsigned uu_[4] = {(unsigned)VR[wv_].x, (unsigned)VR[wv_].y,             \
                         (unsigned)VR[wv_].z, (unsigned)VR[wv_].w};            \
      _Pragma("unroll")                                                        \
      for (int j2_ = 0; j2_ < 4; ++j2_) {                                      \
        float lo_ = __uint_as_float(uu_[j2_] << 16);                           \
        float hi_ = __uint_as_float(uu_[j2_] & 0xffff0000u);                   \
        tmp_[wv_ * 8 + j2_ * 2]     = (__bf16)(lo_ * (WC));                    \
        tmp_[wv_ * 8 + j2_ * 2 + 1] = (__bf16)(hi_ * (WC));                    \
      }                                                                        \
    }                                                                          \
    __bf16* dst_ = &(BUF)[tid * 32];                                           \
    int sela_ = (tid >> 1) & 3;                                                \
    *(int4*)&dst_[(0 ^ sela_) << 3] = *(const int4*)&tmp_[0];                  \
    *(int4*)&dst_[(1 ^ sela_) << 3] = *(const int4*)&tmp_[8];                  \
    *(int4*)&dst_[(2 ^ sela_) << 3] = *(const int4*)&tmp_[16];                 \
    *(int4*)&dst_[(3 ^ sela_) << 3] = *(const int4*)&tmp_[24];                 \
  }                                                                            \
} while (0)

// issue pwt loads for KD into br0..br2 (written to LDS next phase)
#define LOAD_B(KD) do {                                                        \
  const __bf16* __restrict__ bsrc_ = pwt + (size_t)(g * 16 + (KD)) * 9216;     \
  br0 = *(const int4*)&bsrc_[(tid >> 2) * 32 + (tid & 3) * 8];                 \
  br1 = *(const int4*)&bsrc_[((512 + tid) >> 2) * 32 + ((512 + tid) & 3) * 8]; \
  if (tid < 128)                                                               \
    br2 = *(const int4*)&bsrc_[((1024 + tid) >> 2) * 32 + ((1024 + tid) & 3) * 8]; \
} while (0)

// write prefetched br0..br2 into BUF (row-pair chunk-XOR swizzle)
#define WRITE_B(BUF) do {                                                      \
  { int i_ = tid;        int row_ = i_ >> 2, c_ = i_ & 3;                      \
    *(int4*)&(BUF)[row_ * 32 + ((c_ ^ ((row_ >> 1) & 3)) << 3)] = br0; }       \
  { int i_ = 512 + tid;  int row_ = i_ >> 2, c_ = i_ & 3;                      \
    *(int4*)&(BUF)[row_ * 32 + ((c_ ^ ((row_ >> 1) & 3)) << 3)] = br1; }       \
  if (tid < 128) {                                                             \
    int i_ = 1024 + tid; int row_ = i_ >> 2, c_ = i_ & 3;                      \
    *(int4*)&(BUF)[row_ * 32 + ((c_ ^ ((row_ >> 1) & 3)) << 3)] = br2; }       \
} while (0)

#define GATHER(VR, WC, IND, W) do {                                            \
  int ind_ = (IND);                                                            \
  VR[0] = VR[1] = VR[2] = VR[3] = make_int4(0, 0, 0, 0);                       \
  if (inb) {                                                                   \
    int ny_ = gy + ind_ / 7 - 3, nx_ = gx + ind_ % 7 - 3;                      \
    if ((unsigned)ny_ < 96u && (unsigned)nx_ < 96u) {                          \
      const int4* __restrict__ vp_ =                                           \
          (const int4*)(vbase + (size_t)(ny_ * 96 + nx_) * 32);                \
      VR[0] = vp_[0]; VR[1] = vp_[1]; VR[2] = vp_[2]; VR[3] = vp_[3];          \
    }                                                                          \
  }                                                                            \
  WC = (W);                                                                    \
} while (0)

#define MFMA_PHASE(AB, BB) do {                                                \
  _Pragma("unroll")                                                            \
  for (int dx2_ = 0; dx2_ < 3; ++dx2_) {                                       \
    bf16x8 a_[4];                                                              \
    _Pragma("unroll")                                                          \
    for (int r_ = 0; r_ < 4; ++r_) {                                           \
      int p_ = (wid * 2 + r_) * 18 + lr + dx2_;                                \
      a_[r_] = *(const bf16x8*)&(AB)[p_ * 32 + ((kg ^ ((p_ >> 1) & 3)) << 3)]; \
    }                                                                          \
    _Pragma("unroll")                                                          \
    for (int dy2_ = 0; dy2_ < 3; ++dy2_) {                                     \
      int d_ = dy2_ * 3 + dx2_;                                                \
      bf16x8 b0_ = *(const bf16x8*)&(BB)[(d_ * 32 + lr) * 32 + bswz];          \
      bf16x8 b1_ = *(const bf16x8*)&(BB)[(d_ * 32 + 16 + lr) * 32 + bswz];     \
      acc[0][0] = __builtin_amdgcn_mfma_f32_16x16x32_bf16(a_[dy2_],     b0_, acc[0][0], 0, 0, 0); \
      acc[0][1] = __builtin_amdgcn_mfma_f32_16x16x32_bf16(a_[dy2_],     b1_, acc[0][1], 0, 0, 0); \
      acc[1][0] = __builtin_amdgcn_mfma_f32_16x16x32_bf16(a_[dy2_ + 1], b0_, acc[1][0], 0, 0, 0); \
      acc[1][1] = __builtin_amdgcn_mfma_f32_16x16x32_bf16(a_[dy2_ + 1], b1_, acc[1][1], 0, 0, 0); \
    }                                                                          \
  }                                                                            \
} while (0)

__global__ __launch_bounds__(512) void proj_kernel(
    const __bf16* __restrict__ vb, const float* __restrict__ wgtb, const int* __restrict__ indb,
    const __bf16* __restrict__ pwt, const float* __restrict__ pb, float* __restrict__ outp) {
  __shared__ __align__(16) __bf16 Albuf[2][324 * 32];   // 2 x 20736 B
  __shared__ __align__(16) __bf16 Blbuf[2][288 * 32];   // 2 x 18432 B
  int tid = threadIdx.x;
  int bid = blockIdx.x;
  int wg = (bid & 7) * 72 + (bid >> 3);   // XCD-contiguous remap (576 = 8*72)
  int th = wg / 36;                        // f*4+g
  int tile = wg % 36;
  int g = th & 3;
  int ty0 = (tile / 6) * 16, tx0 = (tile % 6) * 16;
  int lane = tid & 63, wid = tid >> 6;     // wid 0..7
  int kg = lane >> 4, lr = lane & 15;
  int bswz = (kg ^ ((lr >> 1) & 3)) << 3;  // B-read chunk offset (lane-const)

  bool gact = tid < 324;
  int ry = tid / 18, rx = tid % 18;
  int gy = ty0 - 1 + ry, gx = tx0 - 1 + rx;
  bool inb = gact && (unsigned)gy < 96u && (unsigned)gx < 96u;
  const __bf16* __restrict__ vbase = vb + (size_t)th * 9216 * 32;
  size_t pxoff = inb ? (size_t)(gy * 96 + gx) : 0;
  const int*   __restrict__ ibase = indb + ((size_t)th * 9216 + pxoff) * 16;
  const float* __restrict__ wbase = wgtb + ((size_t)th * 9216 + pxoff) * 16;

  f32x4 acc[2][2];
  acc[0][0] = (f32x4)(0.0f); acc[0][1] = (f32x4)(0.0f);
  acc[1][0] = (f32x4)(0.0f); acc[1][1] = (f32x4)(0.0f);

  int4 iw_i = make_int4(0, 0, 0, 0);
  float4 iw_w = make_float4(0.f, 0.f, 0.f, 0.f);
  int4 vr0[4], vr1[4];
  float wc0 = 0.f, wc1 = 0.f;
  int4 br0, br1, br2;
  br0 = br1 = br2 = make_int4(0, 0, 0, 0);

  // prologue: iw block 0; gather kd0 -> stage buf0; B0 -> buf0; issue B1; gather kd1
  if (inb) {
    iw_i = *(const int4*)&ibase[0];
    iw_w = *(const float4*)&wbase[0];
  }
  GATHER(vr0, wc0, iw_i.x, iw_w.x);     // kd 0
  STAGE_A(Albuf[0], vr0, wc0);
  LOAD_B(0);
  WRITE_B(Blbuf[0]);
  LOAD_B(1);                             // in-flight for phase kd0
  GATHER(vr1, wc1, iw_i.y, iw_w.y);      // kd 1
  __syncthreads();

  #pragma unroll 1
  for (int kq = 0; kq < 4; ++kq) {
    int k4 = kq * 4;
    // phase kd=k4+0 (MFMA on buf0): write B(k4+1), stage A(k4+1) -> buf1;
    // issue B(k4+2); gather v(k4+2)
    WRITE_B(Blbuf[1]);
    STAGE_A(Albuf[1], vr1, wc1);
    LOAD_B(k4 + 2);
    GATHER(vr0, wc0, iw_i.z, iw_w.z);
    MFMA_PHASE(Albuf[0], Blbuf[0]);
    __syncthreads();
    // phase kd=k4+1 (MFMA on buf1): write B(k4+2), stage A(k4+2) -> buf0;
    // issue B(k4+3); gather v(k4+3)
    WRITE_B(Blbuf[0]);
    STAGE_A(Albuf[0], vr0, wc0);
    LOAD_B(k4 + 3);
    GATHER(vr1, wc1, iw_i.w, iw_w.w);
    MFMA_PHASE(Albuf[1], Blbuf[1]);
    __syncthreads();
    // phase kd=k4+2 (MFMA on buf0): write B(k4+3), stage A(k4+3) -> buf1;
    // issue B(k4+4); reload iw; gather v(k4+4)
    WRITE_B(Blbuf[1]);
    STAGE_A(Albuf[1], vr1, wc1);
    if (kq < 3) {
      LOAD_B(k4 + 4);
      if (inb) {
        iw_i = *(const int4*)&ibase[k4 + 4];
        iw_w = *(const float4*)&wbase[k4 + 4];
      }
      GATHER(vr0, wc0, iw_i.x, iw_w.x);
    }
    MFMA_PHASE(Albuf[0], Blbuf[0]);
    __syncthreads();
    // phase kd=k4+3 (MFMA on buf1): write B(k4+4), stage A(k4+4) -> buf0;
    // issue B(k4+5); gather v(k4+5)
    if (kq < 3) {
      WRITE_B(Blbuf[0]);
      STAGE_A(Albuf[0], vr0, wc0);
      LOAD_B(k4 + 5);
      GATHER(vr1, wc1, iw_i.y, iw_w.y);
    }
    MFMA_PHASE(Albuf[1], Blbuf[1]);
    __syncthreads();
  }

  // epilogue: D col = lane&15 -> o, D row = kg*4+j -> pixel x
  int x0 = tx0 + kg * 4;
  int f = th >> 2;
  #pragma unroll
  for (int mt = 0; mt < 2; ++mt) {
    int y = ty0 + wid * 2 + mt;
    #pragma unroll
    for (int nt = 0; nt < 2; ++nt) {
      int o = g * 32 + nt * 16 + lr;
      float bias = pb[o];
      float4 res = make_float4(acc[mt][nt][0] + bias, acc[mt][nt][1] + bias,
                               acc[mt][nt][2] + bias, acc[mt][nt][3] + bias);
      *(float4*)&outp[(size_t)(f * 128 + o) * 9216 + y * 96 + x0] = res;
    }
  }
}

// ---------------------------------------------------------------------------
extern "C" void kernel_launch(void* const* d_in, const int* in_sizes, int n_in,
                              void* d_out, int out_size, void* d_ws, size_t ws_size,
                              hipStream_t stream) {
  const float* vid = (const float*)d_in[0];
  const float* lnw = (const float*)d_in[1];
  const float* lnb = (const float*)d_in[2];
  const float* wq  = (const float*)d_in[3];
  const float* bq  = (const float*)d_in[4];
  const float* wk  = (const float*)d_in[5];
  const float* bk  = (const float*)d_in[6];
  const float* wv_ = (const float*)d_in[7];
  const float* bv  = (const float*)d_in[8];
  const float* pw  = (const float*)d_in[9];
  const float* pb  = (const float*)d_in[10];
  float* outp = (float*)d_out;

  const size_t SZ_T  = (size_t)16 * 9216 * 32 * 4;     // q/k fp32 each
  const size_t SZ_TB = (size_t)16 * 9216 * 32 * 2;     // v bf16
  const size_t SZ_W  = (size_t)16 * 9216 * 16 * 4;     // wgt / ind
  const size_t SZ_WT = 128 * 384 * 4;
  const size_t SZ_PW = (size_t)4 * 16 * 9 * 32 * 32 * 2;
  const size_t SZ_MU = (size_t)4 * 9216 * 4;

  char* p = (char*)d_ws;
  float* qb = (float*)p;        p += SZ_T;
  float* kb = (float*)p;        p += SZ_T;
  __bf16* vbbf = (__bf16*)p;    p += SZ_TB;
  float* wgtb = (float*)p;      p += SZ_W;
  int*   indb = (int*)p;        p += SZ_W;
  float* Wt = (float*)p;        p += SZ_WT;
  __bf16* pwt = (__bf16*)p;     p += SZ_PW;
  float* mu = (float*)p;        p += SZ_MU;
  float* rs = (float*)p;

  prep_kernel<<<2496, 256, 0, stream>>>(wq, wk, wv_, pw, Wt, pwt);
  ln_stats_kernel<<<dim3(144, 4), 64, 0, stream>>>(vid, mu, rs);
  qkv_gemm_kernel<<<dim3(3, 288), 512, 0, stream>>>(vid, mu, rs, lnw, lnb, Wt, bq, bk, bv,
                                                    qb, kb, vbbf);
  search_kernel<<<dim3(49, 16), 256, 0, stream>>>(qb, kb, wgtb, indb);
  proj_kernel<<<576, 512, 0, stream>>>(vbbf, wgtb, indb, pwt, pb, outp);
}

// Round 14
// 213.714 us; speedup vs baseline: 1.0150x; 1.0150x over previous
//
#include <hip/hip_runtime.h>

// NonLocalAttentionStack on MI355X.
// Dims: B=1, T=4, C=128, H=W=96, NHEADS=4 (c=32/head), WS=7 (49 cands), PS=3, K=16.
// Pipeline: prep -> ln_stats -> xbf (LN+transpose+bf16) -> QK (fp32 GEMM) +
//           vmfma (bf16 MFMA GEMM for v) -> search (fp32) -> proj (R12 form).

typedef float  f32x4  __attribute__((ext_vector_type(4)));
typedef __bf16 bf16x8 __attribute__((ext_vector_type(8)));

__device__ __forceinline__ float dpp_shr1(float x) {
  return __int_as_float(__builtin_amdgcn_update_dpp(0, __float_as_int(x), 0x111, 0xf, 0xf, false));
}
__device__ __forceinline__ float dpp_shl1(float x) {
  return __int_as_float(__builtin_amdgcn_update_dpp(0, __float_as_int(x), 0x101, 0xf, 0xf, false));
}

// ---------------------------------------------------------------------------
// prep: Wt[c][o=384]; pwt[g][kd][d=9][o=32][i=32] bf16; wvh[o=128][c=128] bf16
// ---------------------------------------------------------------------------
__global__ __launch_bounds__(256) void prep_kernel(
    const float* __restrict__ wq, const float* __restrict__ wk, const float* __restrict__ wv,
    const float* __restrict__ pw, float* __restrict__ Wt, __bf16* __restrict__ pwt,
    __bf16* __restrict__ wvh) {
  int idx = blockIdx.x * 256 + threadIdx.x;
  const int NPW = 4 * 16 * 9 * 32 * 32;  // 589824
  if (idx < NPW) {
    int i  = idx & 31;
    int ol = (idx >> 5) & 31;
    int d  = (idx >> 10) % 9;
    int r  = (idx >> 10) / 9;
    int kd = r & 15;
    int g  = r >> 4;
    int o  = g * 32 + ol;
    pwt[idx] = (__bf16)pw[((o * 32 + i) * 16 + kd) * 9 + d];
  } else if (idx < NPW + 128 * 384) {
    int widx = idx - NPW;
    int o = widx % 384;
    int c = widx / 384;
    const float* __restrict__ src = (o < 128) ? wq : (o < 256 ? wk : wv);
    Wt[widx] = src[(o & 127) * 128 + c];
  } else {
    int vidx = idx - NPW - 128 * 384;
    if (vidx < 128 * 128) wvh[vidx] = (__bf16)wv[vidx];
  }
}

// ---------------------------------------------------------------------------
// LN stats: per-pixel mean / rsqrt(var+eps).  grid (144,4) x 64 threads.
// ---------------------------------------------------------------------------
__global__ __launch_bounds__(64) void ln_stats_kernel(
    const float* __restrict__ vid, float* __restrict__ mu, float* __restrict__ rs) {
  int pix = blockIdx.x * 64 + threadIdx.x;
  int f = blockIdx.y;
  const float* __restrict__ vp = vid + (size_t)f * 128 * 9216 + pix;
  float s = 0.f, s2 = 0.f;
  #pragma unroll 8
  for (int c = 0; c < 128; ++c) { float x = vp[(size_t)c * 9216]; s += x; s2 += x * x; }
  float m_ = s * (1.f / 128.f);
  float v_ = fmaxf(s2 * (1.f / 128.f) - m_ * m_, 0.f);
  mu[f * 9216 + pix] = m_;
  rs[f * 9216 + pix] = rsqrtf(v_ + 1e-6f);
}

// ---------------------------------------------------------------------------
// xbf: LN + transpose + bf16.  Writes xbf[f*9216+pix][ch=128] bf16.
// Block: 128 pix x 128 ch; LDS tile chunk-XOR swizzled (chunk^=((pix>>2)&7)).
// grid (72, 4), 256 threads.
// ---------------------------------------------------------------------------
__global__ __launch_bounds__(256) void xbf_kernel(
    const float* __restrict__ vid, const float* __restrict__ mu, const float* __restrict__ rs,
    const float* __restrict__ lnw, const float* __restrict__ lnb, __bf16* __restrict__ xbf) {
  __shared__ __align__(16) __bf16 tile[128 * 128];   // 32KB
  __shared__ float muL[128], rsL[128], lwS[128], lbS[128];
  int t = threadIdx.x;
  int pf = blockIdx.x * 128;
  int f = blockIdx.y;
  if (t < 128) { muL[t] = mu[f * 9216 + pf + t]; rsL[t] = rs[f * 9216 + pf + t]; }
  else { lwS[t - 128] = lnw[t - 128]; lbS[t - 128] = lnb[t - 128]; }
  __syncthreads();
  #pragma unroll 4
  for (int it = 0; it < 16; ++it) {
    int idx = it * 256 + t;
    int c = idx >> 5, p4 = idx & 31;
    float4 v = *(const float4*)&vid[((size_t)(f * 128 + c)) * 9216 + pf + p4 * 4];
    float xs[4] = {v.x, v.y, v.z, v.w};
    #pragma unroll
    for (int i = 0; i < 4; ++i) {
      int pix = p4 * 4 + i;
      float xn = (xs[i] - muL[pix]) * rsL[pix] * lwS[c] + lbS[c];
      int cp = c ^ (((pix >> 2) & 7) << 3);
      tile[pix * 128 + cp] = (__bf16)xn;
    }
  }
  __syncthreads();
  int pix = t >> 1, half = t & 1;
  __bf16* __restrict__ dst = xbf + ((size_t)(f * 9216) + pf + pix) * 128 + half * 64;
  #pragma unroll
  for (int cc = 0; cc < 8; ++cc) {
    int chunk = half * 8 + cc;
    int cs = chunk ^ ((pix >> 2) & 7);
    *(int4*)&dst[cc * 8] = *(const int4*)&tile[pix * 128 + cs * 8];
  }
}

// ---------------------------------------------------------------------------
// QK GEMM (fp32): 128x128 tile, K=128 in 4x32 chunks, 512 threads, reg-dbuf.
// grid (2, 288); blockIdx.x selects q/k.  Output [t*4+head][pix][c32] fp32.
// ---------------------------------------------------------------------------
__global__ __launch_bounds__(512) void qk_gemm_kernel(
    const float* __restrict__ vid, const float* __restrict__ mu, const float* __restrict__ rs,
    const float* __restrict__ lnw, const float* __restrict__ lnb,
    const float* __restrict__ Wt, const float* __restrict__ bq, const float* __restrict__ bk,
    float* __restrict__ qb, float* __restrict__ kb) {
  __shared__ __align__(16) float Xs[32][128];
  __shared__ __align__(16) float Ws[32][128];
  __shared__ float muL[128], rsL[128], lwS[128], lbS[128];
  int tid = threadIdx.x;
  int mt = blockIdx.y;
  int N0 = blockIdx.x * 128;
  int f  = mt / 72;
  int pf = (mt % 72) * 128;

  if (tid < 128) {
    muL[tid] = mu[f * 9216 + pf + tid];
    rsL[tid] = rs[f * 9216 + pf + tid];
  } else if (tid < 256) {
    int t2 = tid - 128;
    lwS[t2] = lnw[t2];
    lbS[t2] = lnb[t2];
  }

  int tx = tid & 15, ty = tid >> 4;
  int m0 = ty * 4;
  int sm = tid & 127;
  int sk = tid >> 7;
  float acc[4][8];
  #pragma unroll
  for (int a = 0; a < 4; ++a)
    #pragma unroll
    for (int b = 0; b < 8; ++b) acc[a][b] = 0.f;

  const size_t vbase = (size_t)f * 128 * 9216 + pf;
  float xr[8], wr[8];

  #pragma unroll
  for (int it = 0; it < 8; ++it) {
    int kk = sk + 4 * it;
    xr[it] = vid[vbase + (size_t)kk * 9216 + sm];
    wr[it] = Wt[(size_t)kk * 384 + N0 + sm];
  }
  __syncthreads();
  #pragma unroll
  for (int it = 0; it < 8; ++it) {
    int kk = sk + 4 * it;
    Xs[kk][sm] = (xr[it] - muL[sm]) * rsL[sm] * lwS[kk] + lbS[kk];
    Ws[kk][sm] = wr[it];
  }
  __syncthreads();

  for (int kc = 0; kc < 4; ++kc) {
    if (kc < 3) {
      #pragma unroll
      for (int it = 0; it < 8; ++it) {
        int kk = sk + 4 * it;
        int c = (kc + 1) * 32 + kk;
        xr[it] = vid[vbase + (size_t)c * 9216 + sm];
        wr[it] = Wt[(size_t)c * 384 + N0 + sm];
      }
    }
    #pragma unroll 4
    for (int kk = 0; kk < 32; ++kk) {
      float xa[4], wa[8];
      *(float4*)&xa[0] = *(const float4*)&Xs[kk][m0];
      *(float4*)&wa[0] = *(const float4*)&Ws[kk][tx * 4];
      *(float4*)&wa[4] = *(const float4*)&Ws[kk][64 + tx * 4];
      #pragma unroll
      for (int a = 0; a < 4; ++a)
        #pragma unroll
        for (int b = 0; b < 8; ++b)
          acc[a][b] = fmaf(xa[a], wa[b], acc[a][b]);
    }
    if (kc < 3) {
      __syncthreads();
      #pragma unroll
      for (int it = 0; it < 8; ++it) {
        int kk = sk + 4 * it;
        int c = (kc + 1) * 32 + kk;
        Xs[kk][sm] = (xr[it] - muL[sm]) * rsL[sm] * lwS[c] + lbS[c];
        Ws[kk][sm] = wr[it];
      }
      __syncthreads();
    }
  }

  int sel = blockIdx.x;
  int nlo = tx * 4, nhi = 64 + tx * 4;
  int hlo = nlo >> 5, clo = nlo & 31;
  int hhi = nhi >> 5, chi = nhi & 31;
  const float* __restrict__ bias = (sel == 0) ? bq : bk;
  float* __restrict__ dst = (sel == 0) ? qb : kb;
  float4 blo = make_float4(bias[nlo], bias[nlo + 1], bias[nlo + 2], bias[nlo + 3]);
  float4 bhi = make_float4(bias[nhi], bias[nhi + 1], bias[nhi + 2], bias[nhi + 3]);
  size_t base_lo = (size_t)(f * 4 + hlo) * 9216 * 32 + clo;
  size_t base_hi = (size_t)(f * 4 + hhi) * 9216 * 32 + chi;
  #pragma unroll
  for (int a = 0; a < 4; ++a) {
    size_t poff = (size_t)(pf + m0 + a) * 32;
    *(float4*)&dst[base_lo + poff] = make_float4(acc[a][0] + blo.x, acc[a][1] + blo.y,
                                                 acc[a][2] + blo.z, acc[a][3] + blo.w);
    *(float4*)&dst[base_hi + poff] = make_float4(acc[a][4] + bhi.x, acc[a][5] + bhi.y,
                                                 acc[a][6] + bhi.z, acc[a][7] + bhi.w);
  }
}

// ---------------------------------------------------------------------------
// vmfma: v = bf16(X)·bf16(Wv) + bv via MFMA.  Tile 64 pix x 128 out, K=128.
// grid 576 (f*144 + ptile), 256 threads (4 waves: 2m x 2n, wave 32x64).
// LDS 48KB (3 blocks/CU), one barrier.  Frag conv: A m=lr, B n=lr, D m=kg*4+j.
// ---------------------------------------------------------------------------
__global__ __launch_bounds__(256) void vmfma_kernel(
    const __bf16* __restrict__ xbf, const __bf16* __restrict__ wvh,
    const float* __restrict__ bv, __bf16* __restrict__ vbbf) {
  __shared__ __align__(16) __bf16 XL[64 * 128];    // 16KB
  __shared__ __align__(16) __bf16 WL[128 * 128];   // 32KB
  int t = threadIdx.x;
  int bid = blockIdx.x;
  int f = bid / 144;
  int pf = (bid % 144) * 64;

  #pragma unroll
  for (int i = 0; i < 4; ++i) {
    int idx = i * 256 + t;
    int pix = idx >> 4, ck = idx & 15;
    int4 val = *(const int4*)&xbf[((size_t)(f * 9216) + pf + pix) * 128 + ck * 8];
    *(int4*)&XL[pix * 128 + ((ck ^ (pix & 7)) << 3)] = val;
  }
  #pragma unroll
  for (int i = 0; i < 8; ++i) {
    int idx = i * 256 + t;
    int o = idx >> 4, ck = idx & 15;
    int4 val = *(const int4*)&wvh[o * 128 + ck * 8];
    *(int4*)&WL[o * 128 + ((ck ^ (o & 7)) << 3)] = val;
  }
  __syncthreads();

  int lane = t & 63, w = t >> 6;
  int wm = w >> 1, wn = w & 1;
  int kg = lane >> 4, lr = lane & 15;
  f32x4 acc[2][4];
  #pragma unroll
  for (int mf = 0; mf < 2; ++mf)
    #pragma unroll
    for (int nf = 0; nf < 4; ++nf) acc[mf][nf] = (f32x4)(0.0f);

  #pragma unroll
  for (int kc = 0; kc < 4; ++kc) {
    int ck = kc * 4 + kg;
    bf16x8 a[2], b[4];
    #pragma unroll
    for (int mf = 0; mf < 2; ++mf) {
      int pix = wm * 32 + mf * 16 + lr;
      a[mf] = *(const bf16x8*)&XL[pix * 128 + ((ck ^ (pix & 7)) << 3)];
    }
    #pragma unroll
    for (int nf = 0; nf < 4; ++nf) {
      int o = wn * 64 + nf * 16 + lr;
      b[nf] = *(const bf16x8*)&WL[o * 128 + ((ck ^ (o & 7)) << 3)];
    }
    #pragma unroll
    for (int mf = 0; mf < 2; ++mf)
      #pragma unroll
      for (int nf = 0; nf < 4; ++nf)
        acc[mf][nf] = __builtin_amdgcn_mfma_f32_16x16x32_bf16(a[mf], b[nf], acc[mf][nf], 0, 0, 0);
  }

  #pragma unroll
  for (int mf = 0; mf < 2; ++mf) {
    #pragma unroll
    for (int nf = 0; nf < 4; ++nf) {
      int o = wn * 64 + nf * 16 + lr;
      int head = o >> 5, c = o & 31;
      float bias = bv[o];
      #pragma unroll
      for (int j = 0; j < 4; ++j) {
        int pix = wm * 32 + mf * 16 + kg * 4 + j;
        vbbf[((size_t)((f * 4 + head) * 9216) + pf + pix) * 32 + c] =
            (__bf16)(acc[mf][nf][j] + bias);
      }
    }
  }
}

// ---------------------------------------------------------------------------
// search + topk + softmax.  16x16 s-region tile, batched 7-dx rounds.
// grid (49, 16), 256 threads, 3 blocks/CU.
// ---------------------------------------------------------------------------
__global__ __launch_bounds__(256, 3) void search_kernel(
    const float* __restrict__ qb, const float* __restrict__ kb,
    float* __restrict__ wgtb, int* __restrict__ indb) {
  __shared__ __align__(16) float klds[16 * 22 * 32];   // 45056 B
  __shared__ float slds[7][256];
  int tid = threadIdx.x;
  int th = blockIdx.y;
  int tile = blockIdx.x;
  int iy0 = (tile / 7) * 14, ix0 = (tile % 7) * 14;
  const float* __restrict__ kbase = kb + (size_t)th * 9216 * 32;

  #pragma unroll
  for (int it = 0; it < 11; ++it) {
    int i = it * 256 + tid;
    int r = i / 176, rem = i % 176;
    int col = rem >> 3, c4 = rem & 7;
    int gy = iy0 - 4 + r, gx = ix0 - 4 + col;
    float4 val = make_float4(0.f, 0.f, 0.f, 0.f);
    if ((unsigned)gy < 96u && (unsigned)gx < 96u)
      val = *(const float4*)&kbase[(size_t)(gy * 96 + gx) * 32 + c4 * 4];
    int p = r * 22 + col;
    *(float4*)&klds[p * 32 + ((c4 ^ (p & 7)) << 2)] = val;
  }

  int sy = tid >> 4, sx = tid & 15;
  int qy = iy0 - 1 + sy, qx = ix0 - 1 + sx;
  bool qok = (unsigned)qy < 96u && (unsigned)qx < 96u;
  float4 qv[8];
  #pragma unroll
  for (int j = 0; j < 8; ++j) qv[j] = make_float4(0.f, 0.f, 0.f, 0.f);
  if (qok) {
    const float* __restrict__ qp = qb + ((size_t)th * 9216 + qy * 96 + qx) * 32;
    #pragma unroll
    for (int j = 0; j < 8; ++j) qv[j] = *(const float4*)&qp[j * 4];
  }
  bool inner = (sy >= 1) && (sy <= 14) && (sx >= 1) && (sx <= 14) && qok;

  float tv[16]; int tix[16];
  #pragma unroll
  for (int j = 0; j < 16; ++j) { tv[j] = -3.0e38f; tix[j] = 0; }
  __syncthreads();

  #pragma unroll 1
  for (int dy = 0; dy < 7; ++dy) {
    if (dy > 0) {
      if (tid < 176) {
        int col = tid >> 3, c4 = tid & 7;
        int r = dy + 15;
        int gy = iy0 - 4 + r, gx = ix0 - 4 + col;
        float4 val = make_float4(0.f, 0.f, 0.f, 0.f);
        if ((unsigned)gy < 96u && (unsigned)gx < 96u)
          val = *(const float4*)&kbase[(size_t)(gy * 96 + gx) * 32 + c4 * 4];
        int p = (r & 15) * 22 + col;
        *(float4*)&klds[p * 32 + ((c4 ^ (p & 7)) << 2)] = val;
      }
      __syncthreads();
    }
    float h[7];
    #pragma unroll
    for (int dx = 0; dx < 7; ++dx) {
      int p = ((sy + dy) & 15) * 22 + (sx + dx);
      const float* __restrict__ kp = &klds[p * 32];
      int sw = p & 7;
      float sdot = 0.f;
      #pragma unroll
      for (int j = 0; j < 8; ++j) {
        float4 kq = *(const float4*)&kp[(j ^ sw) << 2];
        sdot += qv[j].x * kq.x + qv[j].y * kq.y + qv[j].z * kq.z + qv[j].w * kq.w;
      }
      h[dx] = sdot + dpp_shr1(sdot) + dpp_shl1(sdot);
      slds[dx][tid] = h[dx];
    }
    __syncthreads();
    if (inner) {
      #pragma unroll
      for (int dx = 0; dx < 7; ++dx) {
        float sc = h[dx] + slds[dx][tid - 16] + slds[dx][tid + 16];
        int oi = dy * 7 + dx;
        float cv = sc; int ci = oi;
        #pragma unroll
        for (int j = 0; j < 16; ++j) {
          bool gt = cv > tv[j];
          float mx = fmaxf(tv[j], cv);
          float mn = fminf(tv[j], cv);
          int nt = gt ? ci : tix[j];
          ci = gt ? tix[j] : ci;
          tv[j] = mx; cv = mn; tix[j] = nt;
        }
      }
    }
  }

  if (inner) {
    float mx = tv[0];
    float e[16], ssum = 0.f;
    #pragma unroll
    for (int j = 0; j < 16; ++j) { e[j] = __expf(tv[j] - mx); ssum += e[j]; }
    float inv = 1.f / ssum;
    size_t base = ((size_t)th * 9216 + qy * 96 + qx) * 16;
    #pragma unroll
    for (int j = 0; j < 4; ++j) {
      *(float4*)&wgtb[base + j * 4] =
          make_float4(e[j*4] * inv, e[j*4+1] * inv, e[j*4+2] * inv, e[j*4+3] * inv);
      *(int4*)&indb[base + j * 4] = make_int4(tix[j*4], tix[j*4+1], tix[j*4+2], tix[j*4+3]);
    }
  }
}

// ---------------------------------------------------------------------------
// fused gather + implicit-conv GEMM (R12 form): XCD-swizzled, LDS dbuf,
// ONE barrier per kd, row-pair chunk-XOR swizzle (0 conflicts measured).
// ---------------------------------------------------------------------------
#define STAGE_A(BUF, VR, WC) do {                                              \
  if (gact) {                                                                  \
    __bf16 tmp_[32];                                                           \
    _Pragma("unroll")                                                          \
    for (int wv_ = 0; wv_ < 4; ++wv_) {                                        \
      unsigned uu_[4] = {(unsigned)VR[wv_].x, (unsigned)VR[wv_].y,             \
                         (unsigned)VR[wv_].z, (unsigned)VR[wv_].w};            \
      _Pragma("unroll")                                                        \
      for (int j2_ = 0; j2_ < 4; ++j2_) {                                      \
        float lo_ = __uint_as_float(uu_[j2_] << 16);                           \
        float hi_ = __uint_as_float(uu_[j2_] & 0xffff0000u);                   \
        tmp_[wv_ * 8 + j2_ * 2]     = (__bf16)(lo_ * (WC));                    \
        tmp_[wv_ * 8 + j2_ * 2 + 1] = (__bf16)(hi_ * (WC));                    \
      }                                                                        \
    }                                                                          \
    __bf16* dst_ = &(BUF)[tid * 32];                                           \
    int sela_ = (tid >> 1) & 3;                                                \
    *(int4*)&dst_[(0 ^ sela_) << 3] = *(const int4*)&tmp_[0];                  \
    *(int4*)&dst_[(1 ^ sela_) << 3] = *(const int4*)&tmp_[8];                  \
    *(int4*)&dst_[(2 ^ sela_) << 3] = *(const int4*)&tmp_[16];                 \
    *(int4*)&dst_[(3 ^ sela_) << 3] = *(const int4*)&tmp_[24];                 \
  }                                                                            \
} while (0)

#define STAGE_B(BUF, KD) do {                                                  \
  const __bf16* __restrict__ bsrc_ = pwt + (size_t)(g * 16 + (KD)) * 9216;     \
  _Pragma("unroll")                                                            \
  for (int itb_ = 0; itb_ < 3; ++itb_) {                                       \
    int i_ = itb_ * 512 + tid;                                                 \
    if (i_ < 1152) {                                                           \
      int row_ = i_ >> 2, c_ = i_ & 3;                                         \
      *(int4*)&(BUF)[row_ * 32 + ((c_ ^ ((row_ >> 1) & 3)) << 3)] =            \
          *(const int4*)&bsrc_[row_ * 32 + c_ * 8];                            \
    }                                                                          \
  }                                                                            \
} while (0)

#define GATHER(VR, WC, IND, W) do {                                            \
  int ind_ = (IND);                                                            \
  VR[0] = VR[1] = VR[2] = VR[3] = make_int4(0, 0, 0, 0);                       \
  if (inb) {                                                                   \
    int ny_ = gy + ind_ / 7 - 3, nx_ = gx + ind_ % 7 - 3;                      \
    if ((unsigned)ny_ < 96u && (unsigned)nx_ < 96u) {                          \
      const int4* __restrict__ vp_ =                                           \
          (const int4*)(vbase + (size_t)(ny_ * 96 + nx_) * 32);                \
      VR[0] = vp_[0]; VR[1] = vp_[1]; VR[2] = vp_[2]; VR[3] = vp_[3];          \
    }                                                                          \
  }                                                                            \
  WC = (W);                                                                    \
} while (0)

#define MFMA_PHASE(AB, BB) do {                                                \
  _Pragma("unroll")                                                            \
  for (int dx2_ = 0; dx2_ < 3; ++dx2_) {                                       \
    bf16x8 a_[4];                                                              \
    _Pragma("unroll")                                                          \
    for (int r_ = 0; r_ < 4; ++r_) {                                           \
      int p_ = (wid * 2 + r_) * 18 + lr + dx2_;                                \
      a_[r_] = *(const bf16x8*)&(AB)[p_ * 32 + ((kg ^ ((p_ >> 1) & 3)) << 3)]; \
    }                                                                          \
    _Pragma("unroll")                                                          \
    for (int dy2_ = 0; dy2_ < 3; ++dy2_) {                                     \
      int d_ = dy2_ * 3 + dx2_;                                                \
      bf16x8 b0_ = *(const bf16x8*)&(BB)[(d_ * 32 + lr) * 32 + bswz];          \
      bf16x8 b1_ = *(const bf16x8*)&(BB)[(d_ * 32 + 16 + lr) * 32 + bswz];     \
      acc[0][0] = __builtin_amdgcn_mfma_f32_16x16x32_bf16(a_[dy2_],     b0_, acc[0][0], 0, 0, 0); \
      acc[0][1] = __builtin_amdgcn_mfma_f32_16x16x32_bf16(a_[dy2_],     b1_, acc[0][1], 0, 0, 0); \
      acc[1][0] = __builtin_amdgcn_mfma_f32_16x16x32_bf16(a_[dy2_ + 1], b0_, acc[1][0], 0, 0, 0); \
      acc[1][1] = __builtin_amdgcn_mfma_f32_16x16x32_bf16(a_[dy2_ + 1], b1_, acc[1][1], 0, 0, 0); \
    }                                                                          \
  }                                                                            \
} while (0)

__global__ __launch_bounds__(512) void proj_kernel(
    const __bf16* __restrict__ vb, const float* __restrict__ wgtb, const int* __restrict__ indb,
    const __bf16* __restrict__ pwt, const float* __restrict__ pb, float* __restrict__ outp) {
  __shared__ __align__(16) __bf16 Albuf[2][324 * 32];
  __shared__ __align__(16) __bf16 Blbuf[2][288 * 32];
  int tid = threadIdx.x;
  int bid = blockIdx.x;
  int wg = (bid & 7) * 72 + (bid >> 3);
  int th = wg / 36;
  int tile = wg % 36;
  int g = th & 3;
  int ty0 = (tile / 6) * 16, tx0 = (tile % 6) * 16;
  int lane = tid & 63, wid = tid >> 6;
  int kg = lane >> 4, lr = lane & 15;
  int bswz = (kg ^ ((lr >> 1) & 3)) << 3;

  bool gact = tid < 324;
  int ry = tid / 18, rx = tid % 18;
  int gy = ty0 - 1 + ry, gx = tx0 - 1 + rx;
  bool inb = gact && (unsigned)gy < 96u && (unsigned)gx < 96u;
  const __bf16* __restrict__ vbase = vb + (size_t)th * 9216 * 32;
  size_t pxoff = inb ? (size_t)(gy * 96 + gx) : 0;
  const int*   __restrict__ ibase = indb + ((size_t)th * 9216 + pxoff) * 16;
  const float* __restrict__ wbase = wgtb + ((size_t)th * 9216 + pxoff) * 16;

  f32x4 acc[2][2];
  acc[0][0] = (f32x4)(0.0f); acc[0][1] = (f32x4)(0.0f);
  acc[1][0] = (f32x4)(0.0f); acc[1][1] = (f32x4)(0.0f);

  int4 iw_i = make_int4(0, 0, 0, 0);
  float4 iw_w = make_float4(0.f, 0.f, 0.f, 0.f);
  int4 vr0[4], vr1[4];
  float wc0 = 0.f, wc1 = 0.f;

  if (inb) {
    iw_i = *(const int4*)&ibase[0];
    iw_w = *(const float4*)&wbase[0];
  }
  GATHER(vr0, wc0, iw_i.x, iw_w.x);
  STAGE_A(Albuf[0], vr0, wc0);
  STAGE_B(Blbuf[0], 0);
  GATHER(vr1, wc1, iw_i.y, iw_w.y);
  __syncthreads();

  #pragma unroll 1
  for (int kq = 0; kq < 4; ++kq) {
    int k4 = kq * 4;
    STAGE_A(Albuf[1], vr1, wc1);
    STAGE_B(Blbuf[1], k4 + 1);
    GATHER(vr0, wc0, iw_i.z, iw_w.z);
    MFMA_PHASE(Albuf[0], Blbuf[0]);
    __syncthreads();
    STAGE_A(Albuf[0], vr0, wc0);
    STAGE_B(Blbuf[0], k4 + 2);
    GATHER(vr1, wc1, iw_i.w, iw_w.w);
    MFMA_PHASE(Albuf[1], Blbuf[1]);
    __syncthreads();
    STAGE_A(Albuf[1], vr1, wc1);
    STAGE_B(Blbuf[1], k4 + 3);
    if (kq < 3) {
      if (inb) {
        iw_i = *(const int4*)&ibase[k4 + 4];
        iw_w = *(const float4*)&wbase[k4 + 4];
      }
      GATHER(vr0, wc0, iw_i.x, iw_w.x);
    }
    MFMA_PHASE(Albuf[0], Blbuf[0]);
    __syncthreads();
    if (kq < 3) {
      STAGE_A(Albuf[0], vr0, wc0);
      STAGE_B(Blbuf[0], k4 + 4);
      GATHER(vr1, wc1, iw_i.y, iw_w.y);
    }
    MFMA_PHASE(Albuf[1], Blbuf[1]);
    __syncthreads();
  }

  int x0 = tx0 + kg * 4;
  int f = th >> 2;
  #pragma unroll
  for (int mt = 0; mt < 2; ++mt) {
    int y = ty0 + wid * 2 + mt;
    #pragma unroll
    for (int nt = 0; nt < 2; ++nt) {
      int o = g * 32 + nt * 16 + lr;
      float bias = pb[o];
      float4 res = make_float4(acc[mt][nt][0] + bias, acc[mt][nt][1] + bias,
                               acc[mt][nt][2] + bias, acc[mt][nt][3] + bias);
      *(float4*)&outp[(size_t)(f * 128 + o) * 9216 + y * 96 + x0] = res;
    }
  }
}

// ---------------------------------------------------------------------------
extern "C" void kernel_launch(void* const* d_in, const int* in_sizes, int n_in,
                              void* d_out, int out_size, void* d_ws, size_t ws_size,
                              hipStream_t stream) {
  const float* vid = (const float*)d_in[0];
  const float* lnw = (const float*)d_in[1];
  const float* lnb = (const float*)d_in[2];
  const float* wq  = (const float*)d_in[3];
  const float* bq  = (const float*)d_in[4];
  const float* wk  = (const float*)d_in[5];
  const float* bk  = (const float*)d_in[6];
  const float* wv_ = (const float*)d_in[7];
  const float* bv  = (const float*)d_in[8];
  const float* pw  = (const float*)d_in[9];
  const float* pb  = (const float*)d_in[10];
  float* outp = (float*)d_out;

  const size_t SZ_T  = (size_t)16 * 9216 * 32 * 4;     // q/k fp32 each
  const size_t SZ_TB = (size_t)16 * 9216 * 32 * 2;     // v bf16
  const size_t SZ_W  = (size_t)16 * 9216 * 16 * 4;     // wgt / ind
  const size_t SZ_WT = 128 * 384 * 4;
  const size_t SZ_PW = (size_t)4 * 16 * 9 * 32 * 32 * 2;
  const size_t SZ_MU = (size_t)4 * 9216 * 4;
  const size_t SZ_XB = (size_t)4 * 9216 * 128 * 2;     // xbf bf16
  const size_t SZ_WV = 128 * 128 * 2;                  // wvh bf16

  char* p = (char*)d_ws;
  float* qb = (float*)p;        p += SZ_T;
  float* kb = (float*)p;        p += SZ_T;
  __bf16* vbbf = (__bf16*)p;    p += SZ_TB;
  float* wgtb = (float*)p;      p += SZ_W;
  int*   indb = (int*)p;        p += SZ_W;
  float* Wt = (float*)p;        p += SZ_WT;
  __bf16* pwt = (__bf16*)p;     p += SZ_PW;
  float* mu = (float*)p;        p += SZ_MU;
  float* rs = (float*)p;        p += SZ_MU;
  __bf16* xbf = (__bf16*)p;     p += SZ_XB;
  __bf16* wvh = (__bf16*)p;

  prep_kernel<<<2560, 256, 0, stream>>>(wq, wk, wv_, pw, Wt, pwt, wvh);
  ln_stats_kernel<<<dim3(144, 4), 64, 0, stream>>>(vid, mu, rs);
  xbf_kernel<<<dim3(72, 4), 256, 0, stream>>>(vid, mu, rs, lnw, lnb, xbf);
  qk_gemm_kernel<<<dim3(2, 288), 512, 0, stream>>>(vid, mu, rs, lnw, lnb, Wt, bq, bk, qb, kb);
  vmfma_kernel<<<576, 256, 0, stream>>>(xbf, wvh, bv, vbbf);
  search_kernel<<<dim3(49, 16), 256, 0, stream>>>(qb, kb, wgtb, indb);
  proj_kernel<<<576, 512, 0, stream>>>(vbbf, wgtb, indb, pwt, pb, outp);
}

// Round 15
// 212.846 us; speedup vs baseline: 1.0192x; 1.0041x over previous
//
#include <hip/hip_runtime.h>

// NonLocalAttentionStack on MI355X.
// Dims: B=1, T=4, C=128, H=W=96, NHEADS=4 (c=32/head), WS=7 (49 cands), PS=3, K=16.
// Pipeline: prep -> ln_stats -> xbf (LN+transpose+bf16) -> QK (fp32 GEMM,
//           256thr/8x8 acc: halves per-CU DS-pipe cycles) + vmfma (bf16 MFMA v)
//           -> search (fp32) -> proj (R12 form).

typedef float  f32x4  __attribute__((ext_vector_type(4)));
typedef __bf16 bf16x8 __attribute__((ext_vector_type(8)));

__device__ __forceinline__ float dpp_shr1(float x) {
  return __int_as_float(__builtin_amdgcn_update_dpp(0, __float_as_int(x), 0x111, 0xf, 0xf, false));
}
__device__ __forceinline__ float dpp_shl1(float x) {
  return __int_as_float(__builtin_amdgcn_update_dpp(0, __float_as_int(x), 0x101, 0xf, 0xf, false));
}

// ---------------------------------------------------------------------------
// prep: Wt[c][o=384]; pwt[g][kd][d=9][o=32][i=32] bf16; wvh[o=128][c=128] bf16
// ---------------------------------------------------------------------------
__global__ __launch_bounds__(256) void prep_kernel(
    const float* __restrict__ wq, const float* __restrict__ wk, const float* __restrict__ wv,
    const float* __restrict__ pw, float* __restrict__ Wt, __bf16* __restrict__ pwt,
    __bf16* __restrict__ wvh) {
  int idx = blockIdx.x * 256 + threadIdx.x;
  const int NPW = 4 * 16 * 9 * 32 * 32;  // 589824
  if (idx < NPW) {
    int i  = idx & 31;
    int ol = (idx >> 5) & 31;
    int d  = (idx >> 10) % 9;
    int r  = (idx >> 10) / 9;
    int kd = r & 15;
    int g  = r >> 4;
    int o  = g * 32 + ol;
    pwt[idx] = (__bf16)pw[((o * 32 + i) * 16 + kd) * 9 + d];
  } else if (idx < NPW + 128 * 384) {
    int widx = idx - NPW;
    int o = widx % 384;
    int c = widx / 384;
    const float* __restrict__ src = (o < 128) ? wq : (o < 256 ? wk : wv);
    Wt[widx] = src[(o & 127) * 128 + c];
  } else {
    int vidx = idx - NPW - 128 * 384;
    if (vidx < 128 * 128) wvh[vidx] = (__bf16)wv[vidx];
  }
}

// ---------------------------------------------------------------------------
// LN stats: per-pixel mean / rsqrt(var+eps).  grid (144,4) x 64 threads.
// ---------------------------------------------------------------------------
__global__ __launch_bounds__(64) void ln_stats_kernel(
    const float* __restrict__ vid, float* __restrict__ mu, float* __restrict__ rs) {
  int pix = blockIdx.x * 64 + threadIdx.x;
  int f = blockIdx.y;
  const float* __restrict__ vp = vid + (size_t)f * 128 * 9216 + pix;
  float s = 0.f, s2 = 0.f;
  #pragma unroll 8
  for (int c = 0; c < 128; ++c) { float x = vp[(size_t)c * 9216]; s += x; s2 += x * x; }
  float m_ = s * (1.f / 128.f);
  float v_ = fmaxf(s2 * (1.f / 128.f) - m_ * m_, 0.f);
  mu[f * 9216 + pix] = m_;
  rs[f * 9216 + pix] = rsqrtf(v_ + 1e-6f);
}

// ---------------------------------------------------------------------------
// xbf: LN + transpose + bf16.  Writes xbf[f*9216+pix][ch=128] bf16.
// grid (72, 4), 256 threads.
// ---------------------------------------------------------------------------
__global__ __launch_bounds__(256) void xbf_kernel(
    const float* __restrict__ vid, const float* __restrict__ mu, const float* __restrict__ rs,
    const float* __restrict__ lnw, const float* __restrict__ lnb, __bf16* __restrict__ xbf) {
  __shared__ __align__(16) __bf16 tile[128 * 128];   // 32KB
  __shared__ float muL[128], rsL[128], lwS[128], lbS[128];
  int t = threadIdx.x;
  int pf = blockIdx.x * 128;
  int f = blockIdx.y;
  if (t < 128) { muL[t] = mu[f * 9216 + pf + t]; rsL[t] = rs[f * 9216 + pf + t]; }
  else { lwS[t - 128] = lnw[t - 128]; lbS[t - 128] = lnb[t - 128]; }
  __syncthreads();
  #pragma unroll 4
  for (int it = 0; it < 16; ++it) {
    int idx = it * 256 + t;
    int c = idx >> 5, p4 = idx & 31;
    float4 v = *(const float4*)&vid[((size_t)(f * 128 + c)) * 9216 + pf + p4 * 4];
    float xs[4] = {v.x, v.y, v.z, v.w};
    #pragma unroll
    for (int i = 0; i < 4; ++i) {
      int pix = p4 * 4 + i;
      float xn = (xs[i] - muL[pix]) * rsL[pix] * lwS[c] + lbS[c];
      int cp = c ^ (((pix >> 2) & 7) << 3);
      tile[pix * 128 + cp] = (__bf16)xn;
    }
  }
  __syncthreads();
  int pix = t >> 1, half = t & 1;
  __bf16* __restrict__ dst = xbf + ((size_t)(f * 9216) + pf + pix) * 128 + half * 64;
  #pragma unroll
  for (int cc = 0; cc < 8; ++cc) {
    int chunk = half * 8 + cc;
    int cs = chunk ^ ((pix >> 2) & 7);
    *(int4*)&dst[cc * 8] = *(const int4*)&tile[pix * 128 + cs * 8];
  }
}

// ---------------------------------------------------------------------------
// QK GEMM (fp32): 128x128 tile, K=128 in 4x32 chunks, 256 threads, 8x8 acc,
// reg-dbuf staging.  4 b128 LDS reads per 64 FMA (vs 3/32 at 4x8): per-CU
// DS-pipe cycles ~55K vs ~83K.  grid (2, 288); blockIdx.x selects q/k.
// ---------------------------------------------------------------------------
__global__ __launch_bounds__(256) void qk_gemm_kernel(
    const float* __restrict__ vid, const float* __restrict__ mu, const float* __restrict__ rs,
    const float* __restrict__ lnw, const float* __restrict__ lnb,
    const float* __restrict__ Wt, const float* __restrict__ bq, const float* __restrict__ bk,
    float* __restrict__ qb, float* __restrict__ kb) {
  __shared__ __align__(16) float Xs[32][128];
  __shared__ __align__(16) float Ws[32][128];
  __shared__ float muL[128], rsL[128], lwS[128], lbS[128];
  int tid = threadIdx.x;
  int mt = blockIdx.y;
  int N0 = blockIdx.x * 128;
  int f  = mt / 72;
  int pf = (mt % 72) * 128;

  if (tid < 128) {
    muL[tid] = mu[f * 9216 + pf + tid];
    rsL[tid] = rs[f * 9216 + pf + tid];
  } else {
    int t2 = tid - 128;
    lwS[t2] = lnw[t2];
    lbS[t2] = lnb[t2];
  }

  int tx = tid & 15, ty = tid >> 4;   // ty 0..15
  int m0 = ty * 8;
  int sm = tid & 127;                  // staging column
  int sk0 = tid >> 7;                  // staging row parity (0/1)
  float acc[8][8];
  #pragma unroll
  for (int a = 0; a < 8; ++a)
    #pragma unroll
    for (int b = 0; b < 8; ++b) acc[a][b] = 0.f;

  const size_t vbase = (size_t)f * 128 * 9216 + pf;
  float xr[16], wr[16];

  #pragma unroll
  for (int it = 0; it < 16; ++it) {
    int kk = sk0 + 2 * it;
    xr[it] = vid[vbase + (size_t)kk * 9216 + sm];
    wr[it] = Wt[(size_t)kk * 384 + N0 + sm];
  }
  __syncthreads();  // LN stats visible
  #pragma unroll
  for (int it = 0; it < 16; ++it) {
    int kk = sk0 + 2 * it;
    Xs[kk][sm] = (xr[it] - muL[sm]) * rsL[sm] * lwS[kk] + lbS[kk];
    Ws[kk][sm] = wr[it];
  }
  __syncthreads();

  for (int kc = 0; kc < 4; ++kc) {
    if (kc < 3) {
      #pragma unroll
      for (int it = 0; it < 16; ++it) {
        int kk = sk0 + 2 * it;
        int c = (kc + 1) * 32 + kk;
        xr[it] = vid[vbase + (size_t)c * 9216 + sm];
        wr[it] = Wt[(size_t)c * 384 + N0 + sm];
      }
    }
    #pragma unroll 2
    for (int kk = 0; kk < 32; ++kk) {
      float xa[8], wa[8];
      *(float4*)&xa[0] = *(const float4*)&Xs[kk][m0];
      *(float4*)&xa[4] = *(const float4*)&Xs[kk][m0 + 4];
      *(float4*)&wa[0] = *(const float4*)&Ws[kk][tx * 4];
      *(float4*)&wa[4] = *(const float4*)&Ws[kk][64 + tx * 4];
      #pragma unroll
      for (int a = 0; a < 8; ++a)
        #pragma unroll
        for (int b = 0; b < 8; ++b)
          acc[a][b] = fmaf(xa[a], wa[b], acc[a][b]);
    }
    if (kc < 3) {
      __syncthreads();
      #pragma unroll
      for (int it = 0; it < 16; ++it) {
        int kk = sk0 + 2 * it;
        int c = (kc + 1) * 32 + kk;
        Xs[kk][sm] = (xr[it] - muL[sm]) * rsL[sm] * lwS[c] + lbS[c];
        Ws[kk][sm] = wr[it];
      }
      __syncthreads();
    }
  }

  int sel = blockIdx.x;
  int nlo = tx * 4, nhi = 64 + tx * 4;
  int hlo = nlo >> 5, clo = nlo & 31;
  int hhi = nhi >> 5, chi = nhi & 31;
  const float* __restrict__ bias = (sel == 0) ? bq : bk;
  float* __restrict__ dst = (sel == 0) ? qb : kb;
  float4 blo = make_float4(bias[nlo], bias[nlo + 1], bias[nlo + 2], bias[nlo + 3]);
  float4 bhi = make_float4(bias[nhi], bias[nhi + 1], bias[nhi + 2], bias[nhi + 3]);
  size_t base_lo = (size_t)(f * 4 + hlo) * 9216 * 32 + clo;
  size_t base_hi = (size_t)(f * 4 + hhi) * 9216 * 32 + chi;
  #pragma unroll
  for (int a = 0; a < 8; ++a) {
    size_t poff = (size_t)(pf + m0 + a) * 32;
    *(float4*)&dst[base_lo + poff] = make_float4(acc[a][0] + blo.x, acc[a][1] + blo.y,
                                                 acc[a][2] + blo.z, acc[a][3] + blo.w);
    *(float4*)&dst[base_hi + poff] = make_float4(acc[a][4] + bhi.x, acc[a][5] + bhi.y,
                                                 acc[a][6] + bhi.z, acc[a][7] + bhi.w);
  }
}

// ---------------------------------------------------------------------------
// vmfma: v = bf16(X)·bf16(Wv) + bv via MFMA.  Tile 64 pix x 128 out, K=128.
// grid 576, 256 threads.
// ---------------------------------------------------------------------------
__global__ __launch_bounds__(256) void vmfma_kernel(
    const __bf16* __restrict__ xbf, const __bf16* __restrict__ wvh,
    const float* __restrict__ bv, __bf16* __restrict__ vbbf) {
  __shared__ __align__(16) __bf16 XL[64 * 128];    // 16KB
  __shared__ __align__(16) __bf16 WL[128 * 128];   // 32KB
  int t = threadIdx.x;
  int bid = blockIdx.x;
  int f = bid / 144;
  int pf = (bid % 144) * 64;

  #pragma unroll
  for (int i = 0; i < 4; ++i) {
    int idx = i * 256 + t;
    int pix = idx >> 4, ck = idx & 15;
    int4 val = *(const int4*)&xbf[((size_t)(f * 9216) + pf + pix) * 128 + ck * 8];
    *(int4*)&XL[pix * 128 + ((ck ^ (pix & 7)) << 3)] = val;
  }
  #pragma unroll
  for (int i = 0; i < 8; ++i) {
    int idx = i * 256 + t;
    int o = idx >> 4, ck = idx & 15;
    int4 val = *(const int4*)&wvh[o * 128 + ck * 8];
    *(int4*)&WL[o * 128 + ((ck ^ (o & 7)) << 3)] = val;
  }
  __syncthreads();

  int lane = t & 63, w = t >> 6;
  int wm = w >> 1, wn = w & 1;
  int kg = lane >> 4, lr = lane & 15;
  f32x4 acc[2][4];
  #pragma unroll
  for (int mf = 0; mf < 2; ++mf)
    #pragma unroll
    for (int nf = 0; nf < 4; ++nf) acc[mf][nf] = (f32x4)(0.0f);

  #pragma unroll
  for (int kc = 0; kc < 4; ++kc) {
    int ck = kc * 4 + kg;
    bf16x8 a[2], b[4];
    #pragma unroll
    for (int mf = 0; mf < 2; ++mf) {
      int pix = wm * 32 + mf * 16 + lr;
      a[mf] = *(const bf16x8*)&XL[pix * 128 + ((ck ^ (pix & 7)) << 3)];
    }
    #pragma unroll
    for (int nf = 0; nf < 4; ++nf) {
      int o = wn * 64 + nf * 16 + lr;
      b[nf] = *(const bf16x8*)&WL[o * 128 + ((ck ^ (o & 7)) << 3)];
    }
    #pragma unroll
    for (int mf = 0; mf < 2; ++mf)
      #pragma unroll
      for (int nf = 0; nf < 4; ++nf)
        acc[mf][nf] = __builtin_amdgcn_mfma_f32_16x16x32_bf16(a[mf], b[nf], acc[mf][nf], 0, 0, 0);
  }

  #pragma unroll
  for (int mf = 0; mf < 2; ++mf) {
    #pragma unroll
    for (int nf = 0; nf < 4; ++nf) {
      int o = wn * 64 + nf * 16 + lr;
      int head = o >> 5, c = o & 31;
      float bias = bv[o];
      #pragma unroll
      for (int j = 0; j < 4; ++j) {
        int pix = wm * 32 + mf * 16 + kg * 4 + j;
        vbbf[((size_t)((f * 4 + head) * 9216) + pf + pix) * 32 + c] =
            (__bf16)(acc[mf][nf][j] + bias);
      }
    }
  }
}

// ---------------------------------------------------------------------------
// search + topk + softmax.  16x16 s-region tile, batched 7-dx rounds.
// grid (49, 16), 256 threads, 3 blocks/CU.
// ---------------------------------------------------------------------------
__global__ __launch_bounds__(256, 3) void search_kernel(
    const float* __restrict__ qb, const float* __restrict__ kb,
    float* __restrict__ wgtb, int* __restrict__ indb) {
  __shared__ __align__(16) float klds[16 * 22 * 32];   // 45056 B
  __shared__ float slds[7][256];
  int tid = threadIdx.x;
  int th = blockIdx.y;
  int tile = blockIdx.x;
  int iy0 = (tile / 7) * 14, ix0 = (tile % 7) * 14;
  const float* __restrict__ kbase = kb + (size_t)th * 9216 * 32;

  #pragma unroll
  for (int it = 0; it < 11; ++it) {
    int i = it * 256 + tid;
    int r = i / 176, rem = i % 176;
    int col = rem >> 3, c4 = rem & 7;
    int gy = iy0 - 4 + r, gx = ix0 - 4 + col;
    float4 val = make_float4(0.f, 0.f, 0.f, 0.f);
    if ((unsigned)gy < 96u && (unsigned)gx < 96u)
      val = *(const float4*)&kbase[(size_t)(gy * 96 + gx) * 32 + c4 * 4];
    int p = r * 22 + col;
    *(float4*)&klds[p * 32 + ((c4 ^ (p & 7)) << 2)] = val;
  }

  int sy = tid >> 4, sx = tid & 15;
  int qy = iy0 - 1 + sy, qx = ix0 - 1 + sx;
  bool qok = (unsigned)qy < 96u && (unsigned)qx < 96u;
  float4 qv[8];
  #pragma unroll
  for (int j = 0; j < 8; ++j) qv[j] = make_float4(0.f, 0.f, 0.f, 0.f);
  if (qok) {
    const float* __restrict__ qp = qb + ((size_t)th * 9216 + qy * 96 + qx) * 32;
    #pragma unroll
    for (int j = 0; j < 8; ++j) qv[j] = *(const float4*)&qp[j * 4];
  }
  bool inner = (sy >= 1) && (sy <= 14) && (sx >= 1) && (sx <= 14) && qok;

  float tv[16]; int tix[16];
  #pragma unroll
  for (int j = 0; j < 16; ++j) { tv[j] = -3.0e38f; tix[j] = 0; }
  __syncthreads();

  #pragma unroll 1
  for (int dy = 0; dy < 7; ++dy) {
    if (dy > 0) {
      if (tid < 176) {
        int col = tid >> 3, c4 = tid & 7;
        int r = dy + 15;
        int gy = iy0 - 4 + r, gx = ix0 - 4 + col;
        float4 val = make_float4(0.f, 0.f, 0.f, 0.f);
        if ((unsigned)gy < 96u && (unsigned)gx < 96u)
          val = *(const float4*)&kbase[(size_t)(gy * 96 + gx) * 32 + c4 * 4];
        int p = (r & 15) * 22 + col;
        *(float4*)&klds[p * 32 + ((c4 ^ (p & 7)) << 2)] = val;
      }
      __syncthreads();
    }
    float h[7];
    #pragma unroll
    for (int dx = 0; dx < 7; ++dx) {
      int p = ((sy + dy) & 15) * 22 + (sx + dx);
      const float* __restrict__ kp = &klds[p * 32];
      int sw = p & 7;
      float sdot = 0.f;
      #pragma unroll
      for (int j = 0; j < 8; ++j) {
        float4 kq = *(const float4*)&kp[(j ^ sw) << 2];
        sdot += qv[j].x * kq.x + qv[j].y * kq.y + qv[j].z * kq.z + qv[j].w * kq.w;
      }
      h[dx] = sdot + dpp_shr1(sdot) + dpp_shl1(sdot);
      slds[dx][tid] = h[dx];
    }
    __syncthreads();
    if (inner) {
      #pragma unroll
      for (int dx = 0; dx < 7; ++dx) {
        float sc = h[dx] + slds[dx][tid - 16] + slds[dx][tid + 16];
        int oi = dy * 7 + dx;
        float cv = sc; int ci = oi;
        #pragma unroll
        for (int j = 0; j < 16; ++j) {
          bool gt = cv > tv[j];
          float mx = fmaxf(tv[j], cv);
          float mn = fminf(tv[j], cv);
          int nt = gt ? ci : tix[j];
          ci = gt ? tix[j] : ci;
          tv[j] = mx; cv = mn; tix[j] = nt;
        }
      }
    }
  }

  if (inner) {
    float mx = tv[0];
    float e[16], ssum = 0.f;
    #pragma unroll
    for (int j = 0; j < 16; ++j) { e[j] = __expf(tv[j] - mx); ssum += e[j]; }
    float inv = 1.f / ssum;
    size_t base = ((size_t)th * 9216 + qy * 96 + qx) * 16;
    #pragma unroll
    for (int j = 0; j < 4; ++j) {
      *(float4*)&wgtb[base + j * 4] =
          make_float4(e[j*4] * inv, e[j*4+1] * inv, e[j*4+2] * inv, e[j*4+3] * inv);
      *(int4*)&indb[base + j * 4] = make_int4(tix[j*4], tix[j*4+1], tix[j*4+2], tix[j*4+3]);
    }
  }
}

// ---------------------------------------------------------------------------
// fused gather + implicit-conv GEMM (R12 form): XCD-swizzled, LDS dbuf,
// ONE barrier per kd, row-pair chunk-XOR swizzle (0 conflicts measured).
// ---------------------------------------------------------------------------
#define STAGE_A(BUF, VR, WC) do {                                              \
  if (gact) {                                                                  \
    __bf16 tmp_[32];                                                           \
    _Pragma("unroll")                                                          \
    for (int wv_ = 0; wv_ < 4; ++wv_) {                                        \
      unsigned uu_[4] = {(unsigned)VR[wv_].x, (unsigned)VR[wv_].y,             \
                         (unsigned)VR[wv_].z, (unsigned)VR[wv_].w};            \
      _Pragma("unroll")                                                        \
      for (int j2_ = 0; j2_ < 4; ++j2_) {                                      \
        float lo_ = __uint_as_float(uu_[j2_] << 16);                           \
        float hi_ = __uint_as_float(uu_[j2_] & 0xffff0000u);                   \
        tmp_[wv_ * 8 + j2_ * 2]     = (__bf16)(lo_ * (WC));                    \
        tmp_[wv_ * 8 + j2_ * 2 + 1] = (__bf16)(hi_ * (WC));                    \
      }                                                                        \
    }                                                                          \
    __bf16* dst_ = &(BUF)[tid * 32];                                           \
    int sela_ = (tid >> 1) & 3;                                                \
    *(int4*)&dst_[(0 ^ sela_) << 3] = *(const int4*)&tmp_[0];                  \
    *(int4*)&dst_[(1 ^ sela_) << 3] = *(const int4*)&tmp_[8];                  \
    *(int4*)&dst_[(2 ^ sela_) << 3] = *(const int4*)&tmp_[16];                 \
    *(int4*)&dst_[(3 ^ sela_) << 3] = *(const int4*)&tmp_[24];                 \
  }                                                                            \
} while (0)

#define STAGE_B(BUF, KD) do {                                                  \
  const __bf16* __restrict__ bsrc_ = pwt + (size_t)(g * 16 + (KD)) * 9216;     \
  _Pragma("unroll")                                                            \
  for (int itb_ = 0; itb_ < 3; ++itb_) {                                       \
    int i_ = itb_ * 512 + tid;                                                 \
    if (i_ < 1152) {                                                           \
      int row_ = i_ >> 2, c_ = i_ & 3;                                         \
      *(int4*)&(BUF)[row_ * 32 + ((c_ ^ ((row_ >> 1) & 3)) << 3)] =            \
          *(const int4*)&bsrc_[row_ * 32 + c_ * 8];                            \
    }                                                                          \
  }                                                                            \
} while (0)

#define GATHER(VR, WC, IND, W) do {                                            \
  int ind_ = (IND);                                                            \
  VR[0] = VR[1] = VR[2] = VR[3] = make_int4(0, 0, 0, 0);                       \
  if (inb) {                                                                   \
    int ny_ = gy + ind_ / 7 - 3, nx_ = gx + ind_ % 7 - 3;                      \
    if ((unsigned)ny_ < 96u && (unsigned)nx_ < 96u) {                          \
      const int4* __restrict__ vp_ =                                           \
          (const int4*)(vbase + (size_t)(ny_ * 96 + nx_) * 32);                \
      VR[0] = vp_[0]; VR[1] = vp_[1]; VR[2] = vp_[2]; VR[3] = vp_[3];          \
    }                                                                          \
  }                                                                            \
  WC = (W);                                                                    \
} while (0)

#define MFMA_PHASE(AB, BB) do {                                                \
  _Pragma("unroll")                                                            \
  for (int dx2_ = 0; dx2_ < 3; ++dx2_) {                                       \
    bf16x8 a_[4];                                                              \
    _Pragma("unroll")                                                          \
    for (int r_ = 0; r_ < 4; ++r_) {                                           \
      int p_ = (wid * 2 + r_) * 18 + lr + dx2_;                                \
      a_[r_] = *(const bf16x8*)&(AB)[p_ * 32 + ((kg ^ ((p_ >> 1) & 3)) << 3)]; \
    }                                                                          \
    _Pragma("unroll")                                                          \
    for (int dy2_ = 0; dy2_ < 3; ++dy2_) {                                     \
      int d_ = dy2_ * 3 + dx2_;                                                \
      bf16x8 b0_ = *(const bf16x8*)&(BB)[(d_ * 32 + lr) * 32 + bswz];          \
      bf16x8 b1_ = *(const bf16x8*)&(BB)[(d_ * 32 + 16 + lr) * 32 + bswz];     \
      acc[0][0] = __builtin_amdgcn_mfma_f32_16x16x32_bf16(a_[dy2_],     b0_, acc[0][0], 0, 0, 0); \
      acc[0][1] = __builtin_amdgcn_mfma_f32_16x16x32_bf16(a_[dy2_],     b1_, acc[0][1], 0, 0, 0); \
      acc[1][0] = __builtin_amdgcn_mfma_f32_16x16x32_bf16(a_[dy2_ + 1], b0_, acc[1][0], 0, 0, 0); \
      acc[1][1] = __builtin_amdgcn_mfma_f32_16x16x32_bf16(a_[dy2_ + 1], b1_, acc[1][1], 0, 0, 0); \
    }                                                                          \
  }                                                                            \
} while (0)

__global__ __launch_bounds__(512) void proj_kernel(
    const __bf16* __restrict__ vb, const float* __restrict__ wgtb, const int* __restrict__ indb,
    const __bf16* __restrict__ pwt, const float* __restrict__ pb, float* __restrict__ outp) {
  __shared__ __align__(16) __bf16 Albuf[2][324 * 32];
  __shared__ __align__(16) __bf16 Blbuf[2][288 * 32];
  int tid = threadIdx.x;
  int bid = blockIdx.x;
  int wg = (bid & 7) * 72 + (bid >> 3);
  int th = wg / 36;
  int tile = wg % 36;
  int g = th & 3;
  int ty0 = (tile / 6) * 16, tx0 = (tile % 6) * 16;
  int lane = tid & 63, wid = tid >> 6;
  int kg = lane >> 4, lr = lane & 15;
  int bswz = (kg ^ ((lr >> 1) & 3)) << 3;

  bool gact = tid < 324;
  int ry = tid / 18, rx = tid % 18;
  int gy = ty0 - 1 + ry, gx = tx0 - 1 + rx;
  bool inb = gact && (unsigned)gy < 96u && (unsigned)gx < 96u;
  const __bf16* __restrict__ vbase = vb + (size_t)th * 9216 * 32;
  size_t pxoff = inb ? (size_t)(gy * 96 + gx) : 0;
  const int*   __restrict__ ibase = indb + ((size_t)th * 9216 + pxoff) * 16;
  const float* __restrict__ wbase = wgtb + ((size_t)th * 9216 + pxoff) * 16;

  f32x4 acc[2][2];
  acc[0][0] = (f32x4)(0.0f); acc[0][1] = (f32x4)(0.0f);
  acc[1][0] = (f32x4)(0.0f); acc[1][1] = (f32x4)(0.0f);

  int4 iw_i = make_int4(0, 0, 0, 0);
  float4 iw_w = make_float4(0.f, 0.f, 0.f, 0.f);
  int4 vr0[4], vr1[4];
  float wc0 = 0.f, wc1 = 0.f;

  if (inb) {
    iw_i = *(const int4*)&ibase[0];
    iw_w = *(const float4*)&wbase[0];
  }
  GATHER(vr0, wc0, iw_i.x, iw_w.x);
  STAGE_A(Albuf[0], vr0, wc0);
  STAGE_B(Blbuf[0], 0);
  GATHER(vr1, wc1, iw_i.y, iw_w.y);
  __syncthreads();

  #pragma unroll 1
  for (int kq = 0; kq < 4; ++kq) {
    int k4 = kq * 4;
    STAGE_A(Albuf[1], vr1, wc1);
    STAGE_B(Blbuf[1], k4 + 1);
    GATHER(vr0, wc0, iw_i.z, iw_w.z);
    MFMA_PHASE(Albuf[0], Blbuf[0]);
    __syncthreads();
    STAGE_A(Albuf[0], vr0, wc0);
    STAGE_B(Blbuf[0], k4 + 2);
    GATHER(vr1, wc1, iw_i.w, iw_w.w);
    MFMA_PHASE(Albuf[1], Blbuf[1]);
    __syncthreads();
    STAGE_A(Albuf[1], vr1, wc1);
    STAGE_B(Blbuf[1], k4 + 3);
    if (kq < 3) {
      if (inb) {
        iw_i = *(const int4*)&ibase[k4 + 4];
        iw_w = *(const float4*)&wbase[k4 + 4];
      }
      GATHER(vr0, wc0, iw_i.x, iw_w.x);
    }
    MFMA_PHASE(Albuf[0], Blbuf[0]);
    __syncthreads();
    if (kq < 3) {
      STAGE_A(Albuf[0], vr0, wc0);
      STAGE_B(Blbuf[0], k4 + 4);
      GATHER(vr1, wc1, iw_i.y, iw_w.y);
    }
    MFMA_PHASE(Albuf[1], Blbuf[1]);
    __syncthreads();
  }

  int x0 = tx0 + kg * 4;
  int f = th >> 2;
  #pragma unroll
  for (int mt = 0; mt < 2; ++mt) {
    int y = ty0 + wid * 2 + mt;
    #pragma unroll
    for (int nt = 0; nt < 2; ++nt) {
      int o = g * 32 + nt * 16 + lr;
      float bias = pb[o];
      float4 res = make_float4(acc[mt][nt][0] + bias, acc[mt][nt][1] + bias,
                               acc[mt][nt][2] + bias, acc[mt][nt][3] + bias);
      *(float4*)&outp[(size_t)(f * 128 + o) * 9216 + y * 96 + x0] = res;
    }
  }
}

// ---------------------------------------------------------------------------
extern "C" void kernel_launch(void* const* d_in, const int* in_sizes, int n_in,
                              void* d_out, int out_size, void* d_ws, size_t ws_size,
                              hipStream_t stream) {
  const float* vid = (const float*)d_in[0];
  const float* lnw = (const float*)d_in[1];
  const float* lnb = (const float*)d_in[2];
  const float* wq  = (const float*)d_in[3];
  const float* bq  = (const float*)d_in[4];
  const float* wk  = (const float*)d_in[5];
  const float* bk  = (const float*)d_in[6];
  const float* wv_ = (const float*)d_in[7];
  const float* bv  = (const float*)d_in[8];
  const float* pw  = (const float*)d_in[9];
  const float* pb  = (const float*)d_in[10];
  float* outp = (float*)d_out;

  const size_t SZ_T  = (size_t)16 * 9216 * 32 * 4;     // q/k fp32 each
  const size_t SZ_TB = (size_t)16 * 9216 * 32 * 2;     // v bf16
  const size_t SZ_W  = (size_t)16 * 9216 * 16 * 4;     // wgt / ind
  const size_t SZ_WT = 128 * 384 * 4;
  const size_t SZ_PW = (size_t)4 * 16 * 9 * 32 * 32 * 2;
  const size_t SZ_MU = (size_t)4 * 9216 * 4;
  const size_t SZ_XB = (size_t)4 * 9216 * 128 * 2;     // xbf bf16
  const size_t SZ_WV = 128 * 128 * 2;                  // wvh bf16

  char* p = (char*)d_ws;
  float* qb = (float*)p;        p += SZ_T;
  float* kb = (float*)p;        p += SZ_T;
  __bf16* vbbf = (__bf16*)p;    p += SZ_TB;
  float* wgtb = (float*)p;      p += SZ_W;
  int*   indb = (int*)p;        p += SZ_W;
  float* Wt = (float*)p;        p += SZ_WT;
  __bf16* pwt = (__bf16*)p;     p += SZ_PW;
  float* mu = (float*)p;        p += SZ_MU;
  float* rs = (float*)p;        p += SZ_MU;
  __bf16* xbf = (__bf16*)p;     p += SZ_XB;
  __bf16* wvh = (__bf16*)p;

  prep_kernel<<<2560, 256, 0, stream>>>(wq, wk, wv_, pw, Wt, pwt, wvh);
  ln_stats_kernel<<<dim3(144, 4), 64, 0, stream>>>(vid, mu, rs);
  xbf_kernel<<<dim3(72, 4), 256, 0, stream>>>(vid, mu, rs, lnw, lnb, xbf);
  qk_gemm_kernel<<<dim3(2, 288), 256, 0, stream>>>(vid, mu, rs, lnw, lnb, Wt, bq, bk, qb, kb);
  vmfma_kernel<<<576, 256, 0, stream>>>(xbf, wvh, bv, vbbf);
  search_kernel<<<dim3(49, 16), 256, 0, stream>>>(qb, kb, wgtb, indb);
  proj_kernel<<<576, 512, 0, stream>>>(vbbf, wgtb, indb, pwt, pb, outp);
}

// Round 16
// 194.992 us; speedup vs baseline: 1.1125x; 1.0916x over previous
//
#include <hip/hip_runtime.h>

// NonLocalAttentionStack on MI355X.
// Dims: B=1, T=4, C=128, H=W=96, NHEADS=4 (c=32/head), WS=7 (49 cands), PS=3, K=16.
// Pipeline: prep -> ln_stats -> fat1 { QK fp32 GEMM || xbf LN+bf16 } ->
//           fat2 { search+topk+softmax || vmfma bf16 v-GEMM } -> proj (R12 form).
// Fat kernels co-schedule independent stages on one stream (dependency chain:
// (prep,ln) -> (qk||xbf) -> (search||vmfma) -> proj).

typedef float  f32x4  __attribute__((ext_vector_type(4)));
typedef __bf16 bf16x8 __attribute__((ext_vector_type(8)));

__device__ __forceinline__ float dpp_shr1(float x) {
  return __int_as_float(__builtin_amdgcn_update_dpp(0, __float_as_int(x), 0x111, 0xf, 0xf, false));
}
__device__ __forceinline__ float dpp_shl1(float x) {
  return __int_as_float(__builtin_amdgcn_update_dpp(0, __float_as_int(x), 0x101, 0xf, 0xf, false));
}

// ---------------------------------------------------------------------------
// prep: Wt[c][o=384]; pwt[g][kd][d=9][o=32][i=32] bf16; wvh[o=128][c=128] bf16
// ---------------------------------------------------------------------------
__global__ __launch_bounds__(256) void prep_kernel(
    const float* __restrict__ wq, const float* __restrict__ wk, const float* __restrict__ wv,
    const float* __restrict__ pw, float* __restrict__ Wt, __bf16* __restrict__ pwt,
    __bf16* __restrict__ wvh) {
  int idx = blockIdx.x * 256 + threadIdx.x;
  const int NPW = 4 * 16 * 9 * 32 * 32;  // 589824
  if (idx < NPW) {
    int i  = idx & 31;
    int ol = (idx >> 5) & 31;
    int d  = (idx >> 10) % 9;
    int r  = (idx >> 10) / 9;
    int kd = r & 15;
    int g  = r >> 4;
    int o  = g * 32 + ol;
    pwt[idx] = (__bf16)pw[((o * 32 + i) * 16 + kd) * 9 + d];
  } else if (idx < NPW + 128 * 384) {
    int widx = idx - NPW;
    int o = widx % 384;
    int c = widx / 384;
    const float* __restrict__ src = (o < 128) ? wq : (o < 256 ? wk : wv);
    Wt[widx] = src[(o & 127) * 128 + c];
  } else {
    int vidx = idx - NPW - 128 * 384;
    if (vidx < 128 * 128) wvh[vidx] = (__bf16)wv[vidx];
  }
}

// ---------------------------------------------------------------------------
// LN stats: per-pixel mean / rsqrt(var+eps).  grid (144,4) x 64 threads.
// ---------------------------------------------------------------------------
__global__ __launch_bounds__(64) void ln_stats_kernel(
    const float* __restrict__ vid, float* __restrict__ mu, float* __restrict__ rs) {
  int pix = blockIdx.x * 64 + threadIdx.x;
  int f = blockIdx.y;
  const float* __restrict__ vp = vid + (size_t)f * 128 * 9216 + pix;
  float s = 0.f, s2 = 0.f;
  #pragma unroll 8
  for (int c = 0; c < 128; ++c) { float x = vp[(size_t)c * 9216]; s += x; s2 += x * x; }
  float m_ = s * (1.f / 128.f);
  float v_ = fmaxf(s2 * (1.f / 128.f) - m_ * m_, 0.f);
  mu[f * 9216 + pix] = m_;
  rs[f * 9216 + pix] = rsqrtf(v_ + 1e-6f);
}

// ---------------------------------------------------------------------------
// fat1: blocks 0..575 = QK GEMM (fp32, 256thr/8x8, reg-dbuf); 576..863 = xbf.
// shared: 34816 B both branches.
// ---------------------------------------------------------------------------
__global__ __launch_bounds__(256) void fat1_kernel(
    const float* __restrict__ vid, const float* __restrict__ mu, const float* __restrict__ rs,
    const float* __restrict__ lnw, const float* __restrict__ lnb,
    const float* __restrict__ Wt, const float* __restrict__ bq, const float* __restrict__ bk,
    float* __restrict__ qb, float* __restrict__ kb, __bf16* __restrict__ xbf) {
  __shared__ __align__(16) char smem[34816];
  int tid = threadIdx.x;
  int bid = blockIdx.x;
  if (bid < 576) {
    // ---- QK GEMM ----
    float* Xs  = (float*)smem;                    // [32][128]
    float* Ws  = (float*)(smem + 16384);          // [32][128]
    float* muL = (float*)(smem + 32768);
    float* rsL = muL + 128;
    float* lwS = muL + 256;
    float* lbS = muL + 384;
    int sel = bid & 1;
    int mt  = bid >> 1;
    int N0 = sel * 128;
    int f  = mt / 72;
    int pf = (mt % 72) * 128;

    if (tid < 128) {
      muL[tid] = mu[f * 9216 + pf + tid];
      rsL[tid] = rs[f * 9216 + pf + tid];
    } else {
      int t2 = tid - 128;
      lwS[t2] = lnw[t2];
      lbS[t2] = lnb[t2];
    }

    int tx = tid & 15, ty = tid >> 4;
    int m0 = ty * 8;
    int sm = tid & 127;
    int sk0 = tid >> 7;
    float acc[8][8];
    #pragma unroll
    for (int a = 0; a < 8; ++a)
      #pragma unroll
      for (int b = 0; b < 8; ++b) acc[a][b] = 0.f;

    const size_t vbase = (size_t)f * 128 * 9216 + pf;
    float xr[16], wr[16];

    #pragma unroll
    for (int it = 0; it < 16; ++it) {
      int kk = sk0 + 2 * it;
      xr[it] = vid[vbase + (size_t)kk * 9216 + sm];
      wr[it] = Wt[(size_t)kk * 384 + N0 + sm];
    }
    __syncthreads();
    #pragma unroll
    for (int it = 0; it < 16; ++it) {
      int kk = sk0 + 2 * it;
      Xs[kk * 128 + sm] = (xr[it] - muL[sm]) * rsL[sm] * lwS[kk] + lbS[kk];
      Ws[kk * 128 + sm] = wr[it];
    }
    __syncthreads();

    for (int kc = 0; kc < 4; ++kc) {
      if (kc < 3) {
        #pragma unroll
        for (int it = 0; it < 16; ++it) {
          int kk = sk0 + 2 * it;
          int c = (kc + 1) * 32 + kk;
          xr[it] = vid[vbase + (size_t)c * 9216 + sm];
          wr[it] = Wt[(size_t)c * 384 + N0 + sm];
        }
      }
      #pragma unroll 2
      for (int kk = 0; kk < 32; ++kk) {
        float xa[8], wa[8];
        *(float4*)&xa[0] = *(const float4*)&Xs[kk * 128 + m0];
        *(float4*)&xa[4] = *(const float4*)&Xs[kk * 128 + m0 + 4];
        *(float4*)&wa[0] = *(const float4*)&Ws[kk * 128 + tx * 4];
        *(float4*)&wa[4] = *(const float4*)&Ws[kk * 128 + 64 + tx * 4];
        #pragma unroll
        for (int a = 0; a < 8; ++a)
          #pragma unroll
          for (int b = 0; b < 8; ++b)
            acc[a][b] = fmaf(xa[a], wa[b], acc[a][b]);
      }
      if (kc < 3) {
        __syncthreads();
        #pragma unroll
        for (int it = 0; it < 16; ++it) {
          int kk = sk0 + 2 * it;
          int c = (kc + 1) * 32 + kk;
          Xs[kk * 128 + sm] = (xr[it] - muL[sm]) * rsL[sm] * lwS[c] + lbS[c];
          Ws[kk * 128 + sm] = wr[it];
        }
        __syncthreads();
      }
    }

    int nlo = tx * 4, nhi = 64 + tx * 4;
    int hlo = nlo >> 5, clo = nlo & 31;
    int hhi = nhi >> 5, chi = nhi & 31;
    const float* __restrict__ bias = (sel == 0) ? bq : bk;
    float* __restrict__ dst = (sel == 0) ? qb : kb;
    float4 blo = make_float4(bias[nlo], bias[nlo + 1], bias[nlo + 2], bias[nlo + 3]);
    float4 bhi = make_float4(bias[nhi], bias[nhi + 1], bias[nhi + 2], bias[nhi + 3]);
    size_t base_lo = (size_t)(f * 4 + hlo) * 9216 * 32 + clo;
    size_t base_hi = (size_t)(f * 4 + hhi) * 9216 * 32 + chi;
    #pragma unroll
    for (int a = 0; a < 8; ++a) {
      size_t poff = (size_t)(pf + m0 + a) * 32;
      *(float4*)&dst[base_lo + poff] = make_float4(acc[a][0] + blo.x, acc[a][1] + blo.y,
                                                   acc[a][2] + blo.z, acc[a][3] + blo.w);
      *(float4*)&dst[base_hi + poff] = make_float4(acc[a][4] + bhi.x, acc[a][5] + bhi.y,
                                                   acc[a][6] + bhi.z, acc[a][7] + bhi.w);
    }
  } else {
    // ---- xbf: LN + transpose + bf16 ----
    __bf16* tile = (__bf16*)smem;                 // 128*128 bf16 = 32768
    float* muL = (float*)(smem + 32768);
    float* rsL = muL + 128;
    float* lwS = muL + 256;
    float* lbS = muL + 384;
    int r = bid - 576;
    int pf = (r % 72) * 128;
    int f = r / 72;
    if (tid < 128) { muL[tid] = mu[f * 9216 + pf + tid]; rsL[tid] = rs[f * 9216 + pf + tid]; }
    else { lwS[tid - 128] = lnw[tid - 128]; lbS[tid - 128] = lnb[tid - 128]; }
    __syncthreads();
    #pragma unroll 4
    for (int it = 0; it < 16; ++it) {
      int idx = it * 256 + tid;
      int c = idx >> 5, p4 = idx & 31;
      float4 v = *(const float4*)&vid[((size_t)(f * 128 + c)) * 9216 + pf + p4 * 4];
      float xs[4] = {v.x, v.y, v.z, v.w};
      #pragma unroll
      for (int i = 0; i < 4; ++i) {
        int pix = p4 * 4 + i;
        float xn = (xs[i] - muL[pix]) * rsL[pix] * lwS[c] + lbS[c];
        int cp = c ^ (((pix >> 2) & 7) << 3);
        tile[pix * 128 + cp] = (__bf16)xn;
      }
    }
    __syncthreads();
    int pix = tid >> 1, half = tid & 1;
    __bf16* __restrict__ dst = xbf + ((size_t)(f * 9216) + pf + pix) * 128 + half * 64;
    #pragma unroll
    for (int cc = 0; cc < 8; ++cc) {
      int chunk = half * 8 + cc;
      int cs = chunk ^ ((pix >> 2) & 7);
      *(int4*)&dst[cc * 8] = *(const int4*)&tile[pix * 128 + cs * 8];
    }
  }
}

// ---------------------------------------------------------------------------
// fat2: blocks 0..783 = search+topk+softmax; 784..1359 = vmfma.
// shared: 52224 B (search), 49152 (vmfma) -> union 52224, 3 blocks/CU.
// ---------------------------------------------------------------------------
__global__ __launch_bounds__(256, 3) void fat2_kernel(
    const float* __restrict__ qb, const float* __restrict__ kb,
    float* __restrict__ wgtb, int* __restrict__ indb,
    const __bf16* __restrict__ xbf, const __bf16* __restrict__ wvh,
    const float* __restrict__ bv, __bf16* __restrict__ vbbf) {
  __shared__ __align__(16) char smem[52224];
  int tid = threadIdx.x;
  int bid = blockIdx.x;
  if (bid < 784) {
    // ---- search ----
    float* klds = (float*)smem;                      // 16*22*32 = 45056 B
    float (*slds)[256] = (float(*)[256])(smem + 45056);  // 7*256*4 = 7168
    int tile = bid % 49;
    int th = bid / 49;
    int iy0 = (tile / 7) * 14, ix0 = (tile % 7) * 14;
    const float* __restrict__ kbase = kb + (size_t)th * 9216 * 32;

    #pragma unroll
    for (int it = 0; it < 11; ++it) {
      int i = it * 256 + tid;
      int r = i / 176, rem = i % 176;
      int col = rem >> 3, c4 = rem & 7;
      int gy = iy0 - 4 + r, gx = ix0 - 4 + col;
      float4 val = make_float4(0.f, 0.f, 0.f, 0.f);
      if ((unsigned)gy < 96u && (unsigned)gx < 96u)
        val = *(const float4*)&kbase[(size_t)(gy * 96 + gx) * 32 + c4 * 4];
      int p = r * 22 + col;
      *(float4*)&klds[p * 32 + ((c4 ^ (p & 7)) << 2)] = val;
    }

    int sy = tid >> 4, sx = tid & 15;
    int qy = iy0 - 1 + sy, qx = ix0 - 1 + sx;
    bool qok = (unsigned)qy < 96u && (unsigned)qx < 96u;
    float4 qv[8];
    #pragma unroll
    for (int j = 0; j < 8; ++j) qv[j] = make_float4(0.f, 0.f, 0.f, 0.f);
    if (qok) {
      const float* __restrict__ qp = qb + ((size_t)th * 9216 + qy * 96 + qx) * 32;
      #pragma unroll
      for (int j = 0; j < 8; ++j) qv[j] = *(const float4*)&qp[j * 4];
    }
    bool inner = (sy >= 1) && (sy <= 14) && (sx >= 1) && (sx <= 14) && qok;

    float tv[16]; int tix[16];
    #pragma unroll
    for (int j = 0; j < 16; ++j) { tv[j] = -3.0e38f; tix[j] = 0; }
    __syncthreads();

    #pragma unroll 1
    for (int dy = 0; dy < 7; ++dy) {
      if (dy > 0) {
        if (tid < 176) {
          int col = tid >> 3, c4 = tid & 7;
          int r = dy + 15;
          int gy = iy0 - 4 + r, gx = ix0 - 4 + col;
          float4 val = make_float4(0.f, 0.f, 0.f, 0.f);
          if ((unsigned)gy < 96u && (unsigned)gx < 96u)
            val = *(const float4*)&kbase[(size_t)(gy * 96 + gx) * 32 + c4 * 4];
          int p = (r & 15) * 22 + col;
          *(float4*)&klds[p * 32 + ((c4 ^ (p & 7)) << 2)] = val;
        }
        __syncthreads();
      }
      float h[7];
      #pragma unroll
      for (int dx = 0; dx < 7; ++dx) {
        int p = ((sy + dy) & 15) * 22 + (sx + dx);
        const float* __restrict__ kp = &klds[p * 32];
        int sw = p & 7;
        float sdot = 0.f;
        #pragma unroll
        for (int j = 0; j < 8; ++j) {
          float4 kq = *(const float4*)&kp[(j ^ sw) << 2];
          sdot += qv[j].x * kq.x + qv[j].y * kq.y + qv[j].z * kq.z + qv[j].w * kq.w;
        }
        h[dx] = sdot + dpp_shr1(sdot) + dpp_shl1(sdot);
        slds[dx][tid] = h[dx];
      }
      __syncthreads();
      if (inner) {
        #pragma unroll
        for (int dx = 0; dx < 7; ++dx) {
          float sc = h[dx] + slds[dx][tid - 16] + slds[dx][tid + 16];
          int oi = dy * 7 + dx;
          float cv = sc; int ci = oi;
          #pragma unroll
          for (int j = 0; j < 16; ++j) {
            bool gt = cv > tv[j];
            float mx = fmaxf(tv[j], cv);
            float mn = fminf(tv[j], cv);
            int nt = gt ? ci : tix[j];
            ci = gt ? tix[j] : ci;
            tv[j] = mx; cv = mn; tix[j] = nt;
          }
        }
      }
    }

    if (inner) {
      float mx = tv[0];
      float e[16], ssum = 0.f;
      #pragma unroll
      for (int j = 0; j < 16; ++j) { e[j] = __expf(tv[j] - mx); ssum += e[j]; }
      float inv = 1.f / ssum;
      size_t base = ((size_t)th * 9216 + qy * 96 + qx) * 16;
      #pragma unroll
      for (int j = 0; j < 4; ++j) {
        *(float4*)&wgtb[base + j * 4] =
            make_float4(e[j*4] * inv, e[j*4+1] * inv, e[j*4+2] * inv, e[j*4+3] * inv);
        *(int4*)&indb[base + j * 4] = make_int4(tix[j*4], tix[j*4+1], tix[j*4+2], tix[j*4+3]);
      }
    }
  } else {
    // ---- vmfma ----
    __bf16* XL = (__bf16*)smem;                   // 64*128 bf16 = 16384
    __bf16* WL = (__bf16*)(smem + 16384);         // 128*128 bf16 = 32768
    int r = bid - 784;
    int f = r / 144;
    int pf = (r % 144) * 64;

    #pragma unroll
    for (int i = 0; i < 4; ++i) {
      int idx = i * 256 + tid;
      int pix = idx >> 4, ck = idx & 15;
      int4 val = *(const int4*)&xbf[((size_t)(f * 9216) + pf + pix) * 128 + ck * 8];
      *(int4*)&XL[pix * 128 + ((ck ^ (pix & 7)) << 3)] = val;
    }
    #pragma unroll
    for (int i = 0; i < 8; ++i) {
      int idx = i * 256 + tid;
      int o = idx >> 4, ck = idx & 15;
      int4 val = *(const int4*)&wvh[o * 128 + ck * 8];
      *(int4*)&WL[o * 128 + ((ck ^ (o & 7)) << 3)] = val;
    }
    __syncthreads();

    int lane = tid & 63, w = tid >> 6;
    int wm = w >> 1, wn = w & 1;
    int kg = lane >> 4, lr = lane & 15;
    f32x4 acc[2][4];
    #pragma unroll
    for (int mf = 0; mf < 2; ++mf)
      #pragma unroll
      for (int nf = 0; nf < 4; ++nf) acc[mf][nf] = (f32x4)(0.0f);

    #pragma unroll
    for (int kc = 0; kc < 4; ++kc) {
      int ck = kc * 4 + kg;
      bf16x8 a[2], b[4];
      #pragma unroll
      for (int mf = 0; mf < 2; ++mf) {
        int pix = wm * 32 + mf * 16 + lr;
        a[mf] = *(const bf16x8*)&XL[pix * 128 + ((ck ^ (pix & 7)) << 3)];
      }
      #pragma unroll
      for (int nf = 0; nf < 4; ++nf) {
        int o = wn * 64 + nf * 16 + lr;
        b[nf] = *(const bf16x8*)&WL[o * 128 + ((ck ^ (o & 7)) << 3)];
      }
      #pragma unroll
      for (int mf = 0; mf < 2; ++mf)
        #pragma unroll
        for (int nf = 0; nf < 4; ++nf)
          acc[mf][nf] = __builtin_amdgcn_mfma_f32_16x16x32_bf16(a[mf], b[nf], acc[mf][nf], 0, 0, 0);
    }

    #pragma unroll
    for (int mf = 0; mf < 2; ++mf) {
      #pragma unroll
      for (int nf = 0; nf < 4; ++nf) {
        int o = wn * 64 + nf * 16 + lr;
        int head = o >> 5, c = o & 31;
        float bias = bv[o];
        #pragma unroll
        for (int j = 0; j < 4; ++j) {
          int pix = wm * 32 + mf * 16 + kg * 4 + j;
          vbbf[((size_t)((f * 4 + head) * 9216) + pf + pix) * 32 + c] =
              (__bf16)(acc[mf][nf][j] + bias);
        }
      }
    }
  }
}

// ---------------------------------------------------------------------------
// fused gather + implicit-conv GEMM (R12 form): XCD-swizzled, LDS dbuf,
// ONE barrier per kd, row-pair chunk-XOR swizzle (0 conflicts measured).
// ---------------------------------------------------------------------------
#define STAGE_A(BUF, VR, WC) do {                                              \
  if (gact) {                                                                  \
    __bf16 tmp_[32];                                                           \
    _Pragma("unroll")                                                          \
    for (int wv_ = 0; wv_ < 4; ++wv_) {                                        \
      unsigned uu_[4] = {(unsigned)VR[wv_].x, (unsigned)VR[wv_].y,             \
                         (unsigned)VR[wv_].z, (unsigned)VR[wv_].w};            \
      _Pragma("unroll")                                                        \
      for (int j2_ = 0; j2_ < 4; ++j2_) {                                      \
        float lo_ = __uint_as_float(uu_[j2_] << 16);                           \
        float hi_ = __uint_as_float(uu_[j2_] & 0xffff0000u);                   \
        tmp_[wv_ * 8 + j2_ * 2]     = (__bf16)(lo_ * (WC));                    \
        tmp_[wv_ * 8 + j2_ * 2 + 1] = (__bf16)(hi_ * (WC));                    \
      }                                                                        \
    }                                                                          \
    __bf16* dst_ = &(BUF)[tid * 32];                                           \
    int sela_ = (tid >> 1) & 3;                                                \
    *(int4*)&dst_[(0 ^ sela_) << 3] = *(const int4*)&tmp_[0];                  \
    *(int4*)&dst_[(1 ^ sela_) << 3] = *(const int4*)&tmp_[8];                  \
    *(int4*)&dst_[(2 ^ sela_) << 3] = *(const int4*)&tmp_[16];                 \
    *(int4*)&dst_[(3 ^ sela_) << 3] = *(const int4*)&tmp_[24];                 \
  }                                                                            \
} while (0)

#define STAGE_B(BUF, KD) do {                                                  \
  const __bf16* __restrict__ bsrc_ = pwt + (size_t)(g * 16 + (KD)) * 9216;     \
  _Pragma("unroll")                                                            \
  for (int itb_ = 0; itb_ < 3; ++itb_) {                                       \
    int i_ = itb_ * 512 + tid;                                                 \
    if (i_ < 1152) {                                                           \
      int row_ = i_ >> 2, c_ = i_ & 3;                                         \
      *(int4*)&(BUF)[row_ * 32 + ((c_ ^ ((row_ >> 1) & 3)) << 3)] =            \
          *(const int4*)&bsrc_[row_ * 32 + c_ * 8];                            \
    }                                                                          \
  }                                                                            \
} while (0)

#define GATHER(VR, WC, IND, W) do {                                            \
  int ind_ = (IND);                                                            \
  VR[0] = VR[1] = VR[2] = VR[3] = make_int4(0, 0, 0, 0);                       \
  if (inb) {                                                                   \
    int ny_ = gy + ind_ / 7 - 3, nx_ = gx + ind_ % 7 - 3;                      \
    if ((unsigned)ny_ < 96u && (unsigned)nx_ < 96u) {                          \
      const int4* __restrict__ vp_ =                                           \
          (const int4*)(vbase + (size_t)(ny_ * 96 + nx_) * 32);                \
      VR[0] = vp_[0]; VR[1] = vp_[1]; VR[2] = vp_[2]; VR[3] = vp_[3];          \
    }                                                                          \
  }                                                                            \
  WC = (W);                                                                    \
} while (0)

#define MFMA_PHASE(AB, BB) do {                                                \
  _Pragma("unroll")                                                            \
  for (int dx2_ = 0; dx2_ < 3; ++dx2_) {                                       \
    bf16x8 a_[4];                                                              \
    _Pragma("unroll")                                                          \
    for (int r_ = 0; r_ < 4; ++r_) {                                           \
      int p_ = (wid * 2 + r_) * 18 + lr + dx2_;                                \
      a_[r_] = *(const bf16x8*)&(AB)[p_ * 32 + ((kg ^ ((p_ >> 1) & 3)) << 3)]; \
    }                                                                          \
    _Pragma("unroll")                                                          \
    for (int dy2_ = 0; dy2_ < 3; ++dy2_) {                                     \
      int d_ = dy2_ * 3 + dx2_;                                                \
      bf16x8 b0_ = *(const bf16x8*)&(BB)[(d_ * 32 + lr) * 32 + bswz];          \
      bf16x8 b1_ = *(const bf16x8*)&(BB)[(d_ * 32 + 16 + lr) * 32 + bswz];     \
      acc[0][0] = __builtin_amdgcn_mfma_f32_16x16x32_bf16(a_[dy2_],     b0_, acc[0][0], 0, 0, 0); \
      acc[0][1] = __builtin_amdgcn_mfma_f32_16x16x32_bf16(a_[dy2_],     b1_, acc[0][1], 0, 0, 0); \
      acc[1][0] = __builtin_amdgcn_mfma_f32_16x16x32_bf16(a_[dy2_ + 1], b0_, acc[1][0], 0, 0, 0); \
      acc[1][1] = __builtin_amdgcn_mfma_f32_16x16x32_bf16(a_[dy2_ + 1], b1_, acc[1][1], 0, 0, 0); \
    }                                                                          \
  }                                                                            \
} while (0)

__global__ __launch_bounds__(512) void proj_kernel(
    const __bf16* __restrict__ vb, const float* __restrict__ wgtb, const int* __restrict__ indb,
    const __bf16* __restrict__ pwt, const float* __restrict__ pb, float* __restrict__ outp) {
  __shared__ __align__(16) __bf16 Albuf[2][324 * 32];
  __shared__ __align__(16) __bf16 Blbuf[2][288 * 32];
  int tid = threadIdx.x;
  int bid = blockIdx.x;
  int wg = (bid & 7) * 72 + (bid >> 3);
  int th = wg / 36;
  int tile = wg % 36;
  int g = th & 3;
  int ty0 = (tile / 6) * 16, tx0 = (tile % 6) * 16;
  int lane = tid & 63, wid = tid >> 6;
  int kg = lane >> 4, lr = lane & 15;
  int bswz = (kg ^ ((lr >> 1) & 3)) << 3;

  bool gact = tid < 324;
  int ry = tid / 18, rx = tid % 18;
  int gy = ty0 - 1 + ry, gx = tx0 - 1 + rx;
  bool inb = gact && (unsigned)gy < 96u && (unsigned)gx < 96u;
  const __bf16* __restrict__ vbase = vb + (size_t)th * 9216 * 32;
  size_t pxoff = inb ? (size_t)(gy * 96 + gx) : 0;
  const int*   __restrict__ ibase = indb + ((size_t)th * 9216 + pxoff) * 16;
  const float* __restrict__ wbase = wgtb + ((size_t)th * 9216 + pxoff) * 16;

  f32x4 acc[2][2];
  acc[0][0] = (f32x4)(0.0f); acc[0][1] = (f32x4)(0.0f);
  acc[1][0] = (f32x4)(0.0f); acc[1][1] = (f32x4)(0.0f);

  int4 iw_i = make_int4(0, 0, 0, 0);
  float4 iw_w = make_float4(0.f, 0.f, 0.f, 0.f);
  int4 vr0[4], vr1[4];
  float wc0 = 0.f, wc1 = 0.f;

  if (inb) {
    iw_i = *(const int4*)&ibase[0];
    iw_w = *(const float4*)&wbase[0];
  }
  GATHER(vr0, wc0, iw_i.x, iw_w.x);
  STAGE_A(Albuf[0], vr0, wc0);
  STAGE_B(Blbuf[0], 0);
  GATHER(vr1, wc1, iw_i.y, iw_w.y);
  __syncthreads();

  #pragma unroll 1
  for (int kq = 0; kq < 4; ++kq) {
    int k4 = kq * 4;
    STAGE_A(Albuf[1], vr1, wc1);
    STAGE_B(Blbuf[1], k4 + 1);
    GATHER(vr0, wc0, iw_i.z, iw_w.z);
    MFMA_PHASE(Albuf[0], Blbuf[0]);
    __syncthreads();
    STAGE_A(Albuf[0], vr0, wc0);
    STAGE_B(Blbuf[0], k4 + 2);
    GATHER(vr1, wc1, iw_i.w, iw_w.w);
    MFMA_PHASE(Albuf[1], Blbuf[1]);
    __syncthreads();
    STAGE_A(Albuf[1], vr1, wc1);
    STAGE_B(Blbuf[1], k4 + 3);
    if (kq < 3) {
      if (inb) {
        iw_i = *(const int4*)&ibase[k4 + 4];
        iw_w = *(const float4*)&wbase[k4 + 4];
      }
      GATHER(vr0, wc0, iw_i.x, iw_w.x);
    }
    MFMA_PHASE(Albuf[0], Blbuf[0]);
    __syncthreads();
    if (kq < 3) {
      STAGE_A(Albuf[0], vr0, wc0);
      STAGE_B(Blbuf[0], k4 + 4);
      GATHER(vr1, wc1, iw_i.y, iw_w.y);
    }
    MFMA_PHASE(Albuf[1], Blbuf[1]);
    __syncthreads();
  }

  int x0 = tx0 + kg * 4;
  int f = th >> 2;
  #pragma unroll
  for (int mt = 0; mt < 2; ++mt) {
    int y = ty0 + wid * 2 + mt;
    #pragma unroll
    for (int nt = 0; nt < 2; ++nt) {
      int o = g * 32 + nt * 16 + lr;
      float bias = pb[o];
      float4 res = make_float4(acc[mt][nt][0] + bias, acc[mt][nt][1] + bias,
                               acc[mt][nt][2] + bias, acc[mt][nt][3] + bias);
      *(float4*)&outp[(size_t)(f * 128 + o) * 9216 + y * 96 + x0] = res;
    }
  }
}

// ---------------------------------------------------------------------------
extern "C" void kernel_launch(void* const* d_in, const int* in_sizes, int n_in,
                              void* d_out, int out_size, void* d_ws, size_t ws_size,
                              hipStream_t stream) {
  const float* vid = (const float*)d_in[0];
  const float* lnw = (const float*)d_in[1];
  const float* lnb = (const float*)d_in[2];
  const float* wq  = (const float*)d_in[3];
  const float* bq  = (const float*)d_in[4];
  const float* wk  = (const float*)d_in[5];
  const float* bk  = (const float*)d_in[6];
  const float* wv_ = (const float*)d_in[7];
  const float* bv  = (const float*)d_in[8];
  const float* pw  = (const float*)d_in[9];
  const float* pb  = (const float*)d_in[10];
  float* outp = (float*)d_out;

  const size_t SZ_T  = (size_t)16 * 9216 * 32 * 4;     // q/k fp32 each
  const size_t SZ_TB = (size_t)16 * 9216 * 32 * 2;     // v bf16
  const size_t SZ_W  = (size_t)16 * 9216 * 16 * 4;     // wgt / ind
  const size_t SZ_WT = 128 * 384 * 4;
  const size_t SZ_PW = (size_t)4 * 16 * 9 * 32 * 32 * 2;
  const size_t SZ_MU = (size_t)4 * 9216 * 4;
  const size_t SZ_XB = (size_t)4 * 9216 * 128 * 2;     // xbf bf16
  const size_t SZ_WV = 128 * 128 * 2;                  // wvh bf16

  char* p = (char*)d_ws;
  float* qb = (float*)p;        p += SZ_T;
  float* kb = (float*)p;        p += SZ_T;
  __bf16* vbbf = (__bf16*)p;    p += SZ_TB;
  float* wgtb = (float*)p;      p += SZ_W;
  int*   indb = (int*)p;        p += SZ_W;
  float* Wt = (float*)p;        p += SZ_WT;
  __bf16* pwt = (__bf16*)p;     p += SZ_PW;
  float* mu = (float*)p;        p += SZ_MU;
  float* rs = (float*)p;        p += SZ_MU;
  __bf16* xbf = (__bf16*)p;     p += SZ_XB;
  __bf16* wvh = (__bf16*)p;

  prep_kernel<<<2560, 256, 0, stream>>>(wq, wk, wv_, pw, Wt, pwt, wvh);
  ln_stats_kernel<<<dim3(144, 4), 64, 0, stream>>>(vid, mu, rs);
  fat1_kernel<<<864, 256, 0, stream>>>(vid, mu, rs, lnw, lnb, Wt, bq, bk, qb, kb, xbf);
  fat2_kernel<<<1360, 256, 0, stream>>>(qb, kb, wgtb, indb, xbf, wvh, bv, vbbf);
  proj_kernel<<<576, 512, 0, stream>>>(vbbf, wgtb, indb, pwt, pb, outp);
}